// Round 3
// baseline (8751.377 us; speedup 1.0000x reference)
//
#include <hip/hip_runtime.h>

#define B_ 256
#define T_ 128
#define M_ (B_ * T_)
#define DH_ 256

__device__ __forceinline__ float sigf(float x) { return 1.0f / (1.0f + __expf(-x)); }
__device__ __forceinline__ float dot4(float4 a, float4 b) {
  return a.x * b.x + a.y * b.y + a.z * b.z + a.w * b.w;
}

// ---------------------------------------------------------------------------
// prep: combined biases, padded w_ih_d ([1024][256], cols 250..255 = 0),
// zero dfeat pad columns.
// ---------------------------------------------------------------------------
__global__ void prep_kernel(const float* __restrict__ w_ih_d,
                            const float* __restrict__ b_ih_d, const float* __restrict__ b_hh_d,
                            const float* __restrict__ b_ih0, const float* __restrict__ b_hh0,
                            const float* __restrict__ b_ih1, const float* __restrict__ b_hh1,
                            const float* __restrict__ b_ih2, const float* __restrict__ b_hh2,
                            float* __restrict__ wihd, float* __restrict__ dfeat,
                            float* __restrict__ biasd, float* __restrict__ bias0,
                            float* __restrict__ bias1, float* __restrict__ bias2) {
  int idx = blockIdx.x * blockDim.x + threadIdx.x;
  int stride = gridDim.x * blockDim.x;
  for (int i = idx; i < 1024 * 256; i += stride) {
    int j = i >> 8, k = i & 255;
    wihd[i] = (k < 250) ? w_ih_d[j * 250 + k] : 0.0f;
  }
  for (int i = idx; i < M_ * 6; i += stride)         // zero dfeat pad cols 250..255
    dfeat[(size_t)(i / 6) * 256 + 250 + (i % 6)] = 0.0f;
  for (int i = idx; i < 1024; i += stride) biasd[i] = b_ih_d[i] + b_hh_d[i];
  for (int i = idx; i < 512; i += stride) bias0[i] = b_ih0[i] + b_hh0[i];
  for (int i = idx; i < 256; i += stride) bias1[i] = b_ih1[i] + b_hh1[i];
  for (int i = idx; i < 512; i += stride) bias2[i] = b_ih2[i] + b_hh2[i];
}

// ---------------------------------------------------------------------------
// proj_gemm: C[m][n] = (BTX ? umask : 1) * sum_k A[m][k]*W[n][k] + bias[n]
// BTX: A is [B][T][K] with m = t*B+b; else A is [M][K] row-major.
// Tiled fp32 GEMM, 64x64x16, 256 threads, 4x4 per thread.
// ---------------------------------------------------------------------------
#define BK 16
template <bool BTX>
__global__ __launch_bounds__(256) void proj_gemm(
    const float* __restrict__ X, const float* __restrict__ W,
    const float* __restrict__ bias, const float* __restrict__ umask,
    float* __restrict__ C, int K, int N) {
  __shared__ __align__(16) float As[BK][68];
  __shared__ __align__(16) float Ws[BK][68];
  const int tid = threadIdx.x;
  const int n0 = blockIdx.x * 64;
  const int m0 = blockIdx.y * 64;
  const int t = m0 >> 8;
  const int b0 = m0 & (B_ - 1);
  const int lrow = tid >> 2, kq = tid & 3;
  const int tx = tid & 15, ty = tid >> 4;
  const float* Arow;
  if constexpr (BTX) Arow = X + ((size_t)(b0 + lrow) * T_ + t) * K;
  else               Arow = X + (size_t)(m0 + lrow) * K;
  const float* Wrow = W + (size_t)(n0 + lrow) * K;
  float acc[4][4] = {};
  for (int k0 = 0; k0 < K; k0 += BK) {
    if (k0 + BK <= K) {
      float4 av = *reinterpret_cast<const float4*>(Arow + k0 + kq * 4);
      float4 wv = *reinterpret_cast<const float4*>(Wrow + k0 + kq * 4);
      As[kq * 4 + 0][lrow] = av.x; As[kq * 4 + 1][lrow] = av.y;
      As[kq * 4 + 2][lrow] = av.z; As[kq * 4 + 3][lrow] = av.w;
      Ws[kq * 4 + 0][lrow] = wv.x; Ws[kq * 4 + 1][lrow] = wv.y;
      Ws[kq * 4 + 2][lrow] = wv.z; Ws[kq * 4 + 3][lrow] = wv.w;
    } else {
#pragma unroll
      for (int e = 0; e < 4; e++) {
        int k = k0 + kq * 4 + e;
        As[kq * 4 + e][lrow] = (k < K) ? Arow[k] : 0.0f;
        Ws[kq * 4 + e][lrow] = (k < K) ? Wrow[k] : 0.0f;
      }
    }
    __syncthreads();
#pragma unroll
    for (int kk = 0; kk < BK; kk++) {
      float4 a4 = *reinterpret_cast<const float4*>(&As[kk][ty * 4]);
      float4 w4 = *reinterpret_cast<const float4*>(&Ws[kk][tx * 4]);
      float a[4] = {a4.x, a4.y, a4.z, a4.w};
      float w[4] = {w4.x, w4.y, w4.z, w4.w};
#pragma unroll
      for (int i = 0; i < 4; i++)
#pragma unroll
        for (int j = 0; j < 4; j++) acc[i][j] += a[i] * w[j];
    }
    __syncthreads();
  }
  float4 bv = *reinterpret_cast<const float4*>(bias + n0 + tx * 4);
#pragma unroll
  for (int i = 0; i < 4; i++) {
    int m = m0 + ty * 4 + i;
    float um = 1.0f;
    if constexpr (BTX) um = umask[(b0 + ty * 4 + i) * T_ + t];
    float4 o;
    o.x = acc[i][0] * um + bv.x; o.y = acc[i][1] * um + bv.y;
    o.z = acc[i][2] * um + bv.z; o.w = acc[i][3] * um + bv.w;
    *reinterpret_cast<float4*>(C + (size_t)m * N + n0 + tx * 4) = o;
  }
}

// ---------------------------------------------------------------------------
// mod_lstm: per-modality LSTM scan (unchanged, dfeat stride 256).
// ---------------------------------------------------------------------------
template <int H, int F, int COLOFF>
__device__ __forceinline__ void mod_body(
    const float* __restrict__ gx, const float* __restrict__ whh,
    const float* __restrict__ fcw, const float* __restrict__ fcb,
    const float* __restrict__ umask, float* __restrict__ dfeat,
    int b0, int tid, float (*hs)[128], float (*gbuf)[512]) {
  constexpr int H4 = 4 * H;
  constexpr int NG = H4 / 256;
  constexpr int NU = (4 * H) / 256;
  float creg[NU];
#pragma unroll
  for (int q = 0; q < NU; q++) creg[q] = 0.f;
  for (int u = tid; u < 4 * H; u += 256) hs[u / H][u % H] = 0.f;
  __syncthreads();
  for (int t = 0; t < T_; t++) {
    float acc[NG][4];
#pragma unroll
    for (int g = 0; g < NG; g++)
#pragma unroll
      for (int r = 0; r < 4; r++) acc[g][r] = 0.f;
#pragma unroll 4
    for (int k = 0; k < H; k += 4) {
      float4 h4[4];
#pragma unroll
      for (int r = 0; r < 4; r++) h4[r] = *reinterpret_cast<const float4*>(&hs[r][k]);
#pragma unroll
      for (int g = 0; g < NG; g++) {
        const int jj = tid + (g << 8);
        float4 w4 = *reinterpret_cast<const float4*>(&whh[(size_t)jj * H + k]);
#pragma unroll
        for (int r = 0; r < 4; r++) acc[g][r] += dot4(w4, h4[r]);
      }
    }
#pragma unroll
    for (int g = 0; g < NG; g++) {
      const int jj = tid + (g << 8);
#pragma unroll
      for (int r = 0; r < 4; r++)
        gbuf[r][jj] = acc[g][r] + gx[((size_t)t * B_ + b0 + r) * H4 + jj];
    }
    __syncthreads();
#pragma unroll
    for (int q = 0; q < NU; q++) {
      const int u = tid + (q << 8);
      const int r = u / H, j = u % H;
      float i_ = sigf(gbuf[r][j]);
      float f_ = sigf(gbuf[r][H + j]);
      float g_ = tanhf(gbuf[r][2 * H + j]);
      float o_ = sigf(gbuf[r][3 * H + j]);
      float c2 = f_ * creg[q] + i_ * g_;
      creg[q] = c2;
      hs[r][j] = tanhf(o_ * tanhf(c2));
    }
    __syncthreads();
    if (tid < F) {
      const float* fw = fcw + (size_t)tid * H;
      float fb = fcb[tid];
      float a[4];
#pragma unroll
      for (int r = 0; r < 4; r++) a[r] = fb;
#pragma unroll 4
      for (int k = 0; k < H; k += 4) {
        float4 w4 = *reinterpret_cast<const float4*>(&fw[k]);
#pragma unroll
        for (int r = 0; r < 4; r++)
          a[r] += dot4(w4, *reinterpret_cast<const float4*>(&hs[r][k]));
      }
#pragma unroll
      for (int r = 0; r < 4; r++) {
        float um = umask[(b0 + r) * T_ + t];
        dfeat[((size_t)t * B_ + b0 + r) * 256 + COLOFF + tid] = tanhf(a[r]) * um;
      }
    }
  }
}

struct ModParams {
  const float* gx0; const float* gx1; const float* gx2;
  const float* whh0; const float* whh1; const float* whh2;
  const float* fcw0; const float* fcw1; const float* fcw2;
  const float* fcb0; const float* fcb1; const float* fcb2;
};

__global__ __launch_bounds__(256) void mod_lstm(ModParams p,
    const float* __restrict__ umask, float* __restrict__ dfeat) {
  __shared__ __align__(16) float hs[4][128];
  __shared__ __align__(16) float gbuf[4][512];
  const int mi = blockIdx.x >> 6;
  const int b0 = (blockIdx.x & 63) * 4;
  const int tid = threadIdx.x;
  if (mi == 0)      mod_body<128, 100,   0>(p.gx0, p.whh0, p.fcw0, p.fcb0, umask, dfeat, b0, tid, hs, gbuf);
  else if (mi == 1) mod_body< 64,  50, 100>(p.gx1, p.whh1, p.fcw1, p.fcb1, umask, dfeat, b0, tid, hs, gbuf);
  else              mod_body<128, 100, 150>(p.gx2, p.whh2, p.fcw2, p.fcb2, umask, dfeat, b0, tid, hs, gbuf);
}

// ---------------------------------------------------------------------------
// dlg_recur: one block per batch row; full w_hh register-resident.
// 1024 threads = 16 waves; thread t owns gate row t (64 float4 = 256 VGPRs,
// statically indexed). Per step: broadcast-read h[t-1] from LDS, 64 dot4s,
// gate -> gbuf, cell update by threads 0..255, h -> LDS + hall. No cross-
// block coupling at all (batch rows independent) -> zero global sync.
// ---------------------------------------------------------------------------
__global__ __launch_bounds__(1024, 4) void dlg_recur(
    const float* __restrict__ gxd, const float* __restrict__ whh,
    float* __restrict__ hall) {
  __shared__ __align__(16) float hbuf[DH_];
  __shared__ __align__(16) float gbuf[1024];
  const int tid = threadIdx.x;
  const int b = blockIdx.x;

  // weight row -> registers (static indices only; stays in VGPRs)
  float4 w[64];
  const float4* wrow = reinterpret_cast<const float4*>(whh + (size_t)tid * DH_);
#pragma unroll
  for (int i = 0; i < 64; i++) w[i] = wrow[i];

  if (tid < DH_) hbuf[tid] = 0.f;
  float creg = 0.f;  // cell state (meaningful for tid < 256)
  __syncthreads();

  const float* gxp = gxd + (size_t)b * 1024 + tid;  // + t*B*1024 per step
  float gx_cur = gxp[0];
  for (int t = 0; t < T_; t++) {
    float gx_next = (t + 1 < T_) ? gxp[(size_t)(t + 1) * B_ * 1024] : 0.f;
    float a0 = 0.f, a1 = 0.f, a2 = 0.f, a3 = 0.f;
#pragma unroll
    for (int i = 0; i < 64; i += 4) {
      a0 += dot4(w[i + 0], *reinterpret_cast<const float4*>(&hbuf[(i + 0) * 4]));
      a1 += dot4(w[i + 1], *reinterpret_cast<const float4*>(&hbuf[(i + 1) * 4]));
      a2 += dot4(w[i + 2], *reinterpret_cast<const float4*>(&hbuf[(i + 2) * 4]));
      a3 += dot4(w[i + 3], *reinterpret_cast<const float4*>(&hbuf[(i + 3) * 4]));
    }
    gbuf[tid] = (a0 + a1) + (a2 + a3) + gx_cur;  // gx includes biases
    __syncthreads();
    if (tid < DH_) {
      float i_ = sigf(gbuf[tid]);
      float f_ = sigf(gbuf[DH_ + tid]);
      float g_ = tanhf(gbuf[2 * DH_ + tid]);
      float o_ = sigf(gbuf[3 * DH_ + tid]);
      float c2 = f_ * creg + i_ * g_;
      creg = c2;
      float h2 = o_ * tanhf(c2);
      hbuf[tid] = h2;
      hall[((size_t)t * B_ + b) * DH_ + tid] = h2;
    }
    __syncthreads();
    gx_cur = gx_next;
  }
}

// ---------------------------------------------------------------------------
// out_head: fc_out + tanh + smax + log_softmax over all 32768 (t,b) rows.
// ---------------------------------------------------------------------------
__global__ __launch_bounds__(256) void out_head(
    const float* __restrict__ hall, const float* __restrict__ fcow,
    const float* __restrict__ fcob, const float* __restrict__ smw,
    const float* __restrict__ smb, float* __restrict__ out) {
  __shared__ __align__(16) float h_lds[16][260];
  __shared__ __align__(16) float fco[16][132];
  __shared__ float lg[16][6];
  const int tid = threadIdx.x;
  const int m0 = blockIdx.x * 16;
  {
    const float* src = hall + (size_t)m0 * DH_;
    for (int e = tid; e < 1024; e += 256) {
      float4 v = reinterpret_cast<const float4*>(src)[e];
      const int r = e >> 6, k = (e & 63) * 4;
      *reinterpret_cast<float4*>(&h_lds[r][k]) = v;
    }
  }
  __syncthreads();
  {
    const int f = tid & 127, half = tid >> 7;
    float acc[8];
    const float fb = fcob[f];
#pragma unroll
    for (int r = 0; r < 8; r++) acc[r] = fb;
    const float* wrow = fcow + (size_t)f * DH_;
    for (int k = 0; k < DH_; k += 4) {
      float4 w4 = *reinterpret_cast<const float4*>(wrow + k);
#pragma unroll
      for (int r = 0; r < 8; r++)
        acc[r] += dot4(w4, *reinterpret_cast<const float4*>(&h_lds[half * 8 + r][k]));
    }
#pragma unroll
    for (int r = 0; r < 8; r++) fco[half * 8 + r][f] = tanhf(acc[r]);
  }
  __syncthreads();
  if (tid < 96) {
    const int r = tid / 6, cc = tid % 6;
    float a = smb[cc];
    const float* sw = smw + cc * 128;
#pragma unroll 4
    for (int k = 0; k < 128; k++) a += sw[k] * fco[r][k];
    lg[r][cc] = a;
  }
  __syncthreads();
  if (tid < 16) {
    const int m = m0 + tid;
    const int t = m >> 8, b = m & 255;
    float mx = lg[tid][0];
#pragma unroll
    for (int cc = 1; cc < 6; cc++) mx = fmaxf(mx, lg[tid][cc]);
    float ssum = 0.f;
#pragma unroll
    for (int cc = 0; cc < 6; cc++) ssum += __expf(lg[tid][cc] - mx);
    float lse = mx + logf(ssum);
#pragma unroll
    for (int cc = 0; cc < 6; cc++)
      out[((size_t)b * T_ + t) * 6 + cc] = lg[tid][cc] - lse;
  }
}

// ---------------------------------------------------------------------------
extern "C" void kernel_launch(void* const* d_in, const int* in_sizes, int n_in,
                              void* d_out, int out_size, void* d_ws, size_t ws_size,
                              hipStream_t stream) {
  const float* mod0  = (const float*)d_in[0];
  const float* mod1  = (const float*)d_in[1];
  const float* mod2  = (const float*)d_in[2];
  const float* umask = (const float*)d_in[3];
  const float* w_ih0 = (const float*)d_in[4];
  const float* w_hh0 = (const float*)d_in[5];
  const float* b_ih0 = (const float*)d_in[6];
  const float* b_hh0 = (const float*)d_in[7];
  const float* fc_w0 = (const float*)d_in[8];
  const float* fc_b0 = (const float*)d_in[9];
  const float* w_ih1 = (const float*)d_in[10];
  const float* w_hh1 = (const float*)d_in[11];
  const float* b_ih1 = (const float*)d_in[12];
  const float* b_hh1 = (const float*)d_in[13];
  const float* fc_w1 = (const float*)d_in[14];
  const float* fc_b1 = (const float*)d_in[15];
  const float* w_ih2 = (const float*)d_in[16];
  const float* w_hh2 = (const float*)d_in[17];
  const float* b_ih2 = (const float*)d_in[18];
  const float* b_hh2 = (const float*)d_in[19];
  const float* fc_w2 = (const float*)d_in[20];
  const float* fc_b2 = (const float*)d_in[21];
  const float* w_ih_d = (const float*)d_in[22];
  const float* w_hh_d = (const float*)d_in[23];
  const float* b_ih_d = (const float*)d_in[24];
  const float* b_hh_d = (const float*)d_in[25];
  const float* fco_w  = (const float*)d_in[26];
  const float* fco_b  = (const float*)d_in[27];
  const float* sm_w   = (const float*)d_in[28];
  const float* sm_b   = (const float*)d_in[29];

  // workspace layout (floats):
  //   [0, M*1280)  : gx0|gx1|gx2  -> later reused as gxd [0,M*1024) + hall
  float* ws    = (float*)d_ws;
  float* gx0   = ws;                                  // M*512
  float* gx1   = gx0 + (size_t)M_ * 512;              // M*256
  float* gx2   = gx1 + (size_t)M_ * 256;              // M*512
  float* gxd   = ws;                                  // M*1024 (reuse, gx* dead)
  float* hall  = ws + (size_t)M_ * 1024;              // M*256 (reuse gx2 tail)
  float* dfeat = ws + (size_t)M_ * 1280;              // M*256 (stride 256, pad zeroed)
  float* biasd = dfeat + (size_t)M_ * 256;            // 1024
  float* bias0 = biasd + 1024;                        // 512
  float* bias1 = bias0 + 512;                         // 256
  float* bias2 = bias1 + 256;                         // 512
  float* wihd  = bias2 + 512;                         // 1024*256 padded w_ih_d

  prep_kernel<<<64, 256, 0, stream>>>(w_ih_d, b_ih_d, b_hh_d,
      b_ih0, b_hh0, b_ih1, b_hh1, b_ih2, b_hh2,
      wihd, dfeat, biasd, bias0, bias1, bias2);

  proj_gemm<true><<<dim3(8,  M_ / 64), 256, 0, stream>>>(mod0, w_ih0, bias0, umask, gx0, 300, 512);
  proj_gemm<true><<<dim3(4,  M_ / 64), 256, 0, stream>>>(mod1, w_ih1, bias1, umask, gx1, 100, 256);
  proj_gemm<true><<<dim3(8,  M_ / 64), 256, 0, stream>>>(mod2, w_ih2, bias2, umask, gx2, 512, 512);

  ModParams p;
  p.gx0 = gx0; p.gx1 = gx1; p.gx2 = gx2;
  p.whh0 = w_hh0; p.whh1 = w_hh1; p.whh2 = w_hh2;
  p.fcw0 = fc_w0; p.fcw1 = fc_w1; p.fcw2 = fc_w2;
  p.fcb0 = fc_b0; p.fcb1 = fc_b1; p.fcb2 = fc_b2;
  mod_lstm<<<192, 256, 0, stream>>>(p, umask, dfeat);

  // dialogue input projection: gxd = dfeat @ wihd^T + biasd (overwrites gx*)
  proj_gemm<false><<<dim3(16, M_ / 64), 256, 0, stream>>>(dfeat, wihd, biasd, nullptr, gxd, 256, 1024);

  dlg_recur<<<256, 1024, 0, stream>>>(gxd, w_hh_d, hall);

  out_head<<<M_ / 16, 256, 0, stream>>>(hall, fco_w, fco_b, sm_w, sm_b, (float*)d_out);
}

// Round 4
// 2331.085 us; speedup vs baseline: 3.7542x; 3.7542x over previous
//
#include <hip/hip_runtime.h>

#define B_ 256
#define T_ 128
#define M_ (B_ * T_)
#define DH_ 256

__device__ __forceinline__ float sigf(float x) { return 1.0f / (1.0f + __expf(-x)); }
__device__ __forceinline__ float dot4(float4 a, float4 b) {
  return a.x * b.x + a.y * b.y + a.z * b.z + a.w * b.w;
}

typedef _Float16 half2v __attribute__((ext_vector_type(2)));
__device__ __forceinline__ float fdot2f(unsigned int w, unsigned int h, float acc) {
  half2v wv = __builtin_bit_cast(half2v, w);
  half2v hv = __builtin_bit_cast(half2v, h);
#if __has_builtin(__builtin_amdgcn_fdot2)
  return __builtin_amdgcn_fdot2(wv, hv, acc, false);
#else
  return acc + (float)wv[0] * (float)hv[0] + (float)wv[1] * (float)hv[1];
#endif
}
__device__ __forceinline__ unsigned int pk16(float a, float b) {
  unsigned short lo = __builtin_bit_cast(unsigned short, (_Float16)a);
  unsigned short hi = __builtin_bit_cast(unsigned short, (_Float16)b);
  return (unsigned int)lo | ((unsigned int)hi << 16);
}

// ---------------------------------------------------------------------------
// prep: combined biases, padded w_ih_d, zero dfeat pad cols, and fp16-packed
// dialogue recurrent weights:
//   wpk  [1024 rows][96 u32]  = pairs k=0..191   (register-resident part)
//   wldsg[16 j][1024 r][2 p]  = pairs k=192..255 (LDS-resident part)
// ---------------------------------------------------------------------------
__global__ void prep_kernel(const float* __restrict__ w_ih_d, const float* __restrict__ w_hh_d,
                            const float* __restrict__ b_ih_d, const float* __restrict__ b_hh_d,
                            const float* __restrict__ b_ih0, const float* __restrict__ b_hh0,
                            const float* __restrict__ b_ih1, const float* __restrict__ b_hh1,
                            const float* __restrict__ b_ih2, const float* __restrict__ b_hh2,
                            float* __restrict__ wihd, float* __restrict__ dfeat,
                            float* __restrict__ biasd, float* __restrict__ bias0,
                            float* __restrict__ bias1, float* __restrict__ bias2,
                            unsigned int* __restrict__ wpk, unsigned int* __restrict__ wldsg) {
  int idx = blockIdx.x * blockDim.x + threadIdx.x;
  int stride = gridDim.x * blockDim.x;
  for (int i = idx; i < 1024 * 256; i += stride) {
    int j = i >> 8, k = i & 255;
    wihd[i] = (k < 250) ? w_ih_d[j * 250 + k] : 0.0f;
  }
  for (int i = idx; i < M_ * 6; i += stride)
    dfeat[(size_t)(i / 6) * 256 + 250 + (i % 6)] = 0.0f;
  for (int i = idx; i < 1024 * 96; i += stride) {        // reg part
    int r = i / 96, k0 = (i % 96) * 2;
    wpk[i] = pk16(w_hh_d[(size_t)r * 256 + k0], w_hh_d[(size_t)r * 256 + k0 + 1]);
  }
  for (int i = idx; i < 32768; i += stride) {            // LDS part
    int j = i >> 11, rem = i & 2047, r = rem >> 1, p = rem & 1;
    int k0 = 192 + 4 * j + 2 * p;
    wldsg[i] = pk16(w_hh_d[(size_t)r * 256 + k0], w_hh_d[(size_t)r * 256 + k0 + 1]);
  }
  for (int i = idx; i < 1024; i += stride) biasd[i] = b_ih_d[i] + b_hh_d[i];
  for (int i = idx; i < 512; i += stride) bias0[i] = b_ih0[i] + b_hh0[i];
  for (int i = idx; i < 256; i += stride) bias1[i] = b_ih1[i] + b_hh1[i];
  for (int i = idx; i < 512; i += stride) bias2[i] = b_ih2[i] + b_hh2[i];
}

// ---------------------------------------------------------------------------
// proj_gemm: C[m][n] = (BTX ? umask : 1) * sum_k A[m][k]*W[n][k] + bias[n]
// ---------------------------------------------------------------------------
#define BK 16
template <bool BTX>
__global__ __launch_bounds__(256) void proj_gemm(
    const float* __restrict__ X, const float* __restrict__ W,
    const float* __restrict__ bias, const float* __restrict__ umask,
    float* __restrict__ C, int K, int N) {
  __shared__ __align__(16) float As[BK][68];
  __shared__ __align__(16) float Ws[BK][68];
  const int tid = threadIdx.x;
  const int n0 = blockIdx.x * 64;
  const int m0 = blockIdx.y * 64;
  const int t = m0 >> 8;
  const int b0 = m0 & (B_ - 1);
  const int lrow = tid >> 2, kq = tid & 3;
  const int tx = tid & 15, ty = tid >> 4;
  const float* Arow;
  if constexpr (BTX) Arow = X + ((size_t)(b0 + lrow) * T_ + t) * K;
  else               Arow = X + (size_t)(m0 + lrow) * K;
  const float* Wrow = W + (size_t)(n0 + lrow) * K;
  float acc[4][4] = {};
  for (int k0 = 0; k0 < K; k0 += BK) {
    if (k0 + BK <= K) {
      float4 av = *reinterpret_cast<const float4*>(Arow + k0 + kq * 4);
      float4 wv = *reinterpret_cast<const float4*>(Wrow + k0 + kq * 4);
      As[kq * 4 + 0][lrow] = av.x; As[kq * 4 + 1][lrow] = av.y;
      As[kq * 4 + 2][lrow] = av.z; As[kq * 4 + 3][lrow] = av.w;
      Ws[kq * 4 + 0][lrow] = wv.x; Ws[kq * 4 + 1][lrow] = wv.y;
      Ws[kq * 4 + 2][lrow] = wv.z; Ws[kq * 4 + 3][lrow] = wv.w;
    } else {
#pragma unroll
      for (int e = 0; e < 4; e++) {
        int k = k0 + kq * 4 + e;
        As[kq * 4 + e][lrow] = (k < K) ? Arow[k] : 0.0f;
        Ws[kq * 4 + e][lrow] = (k < K) ? Wrow[k] : 0.0f;
      }
    }
    __syncthreads();
#pragma unroll
    for (int kk = 0; kk < BK; kk++) {
      float4 a4 = *reinterpret_cast<const float4*>(&As[kk][ty * 4]);
      float4 w4 = *reinterpret_cast<const float4*>(&Ws[kk][tx * 4]);
      float a[4] = {a4.x, a4.y, a4.z, a4.w};
      float w[4] = {w4.x, w4.y, w4.z, w4.w};
#pragma unroll
      for (int i = 0; i < 4; i++)
#pragma unroll
        for (int j = 0; j < 4; j++) acc[i][j] += a[i] * w[j];
    }
    __syncthreads();
  }
  float4 bv = *reinterpret_cast<const float4*>(bias + n0 + tx * 4);
#pragma unroll
  for (int i = 0; i < 4; i++) {
    int m = m0 + ty * 4 + i;
    float um = 1.0f;
    if constexpr (BTX) um = umask[(b0 + ty * 4 + i) * T_ + t];
    float4 o;
    o.x = acc[i][0] * um + bv.x; o.y = acc[i][1] * um + bv.y;
    o.z = acc[i][2] * um + bv.z; o.w = acc[i][3] * um + bv.w;
    *reinterpret_cast<float4*>(C + (size_t)m * N + n0 + tx * 4) = o;
  }
}

// ---------------------------------------------------------------------------
// mod_lstm: per-modality LSTM scan (unchanged, dfeat stride 256).
// ---------------------------------------------------------------------------
template <int H, int F, int COLOFF>
__device__ __forceinline__ void mod_body(
    const float* __restrict__ gx, const float* __restrict__ whh,
    const float* __restrict__ fcw, const float* __restrict__ fcb,
    const float* __restrict__ umask, float* __restrict__ dfeat,
    int b0, int tid, float (*hs)[128], float (*gbuf)[512]) {
  constexpr int H4 = 4 * H;
  constexpr int NG = H4 / 256;
  constexpr int NU = (4 * H) / 256;
  float creg[NU];
#pragma unroll
  for (int q = 0; q < NU; q++) creg[q] = 0.f;
  for (int u = tid; u < 4 * H; u += 256) hs[u / H][u % H] = 0.f;
  __syncthreads();
  for (int t = 0; t < T_; t++) {
    float acc[NG][4];
#pragma unroll
    for (int g = 0; g < NG; g++)
#pragma unroll
      for (int r = 0; r < 4; r++) acc[g][r] = 0.f;
#pragma unroll 4
    for (int k = 0; k < H; k += 4) {
      float4 h4[4];
#pragma unroll
      for (int r = 0; r < 4; r++) h4[r] = *reinterpret_cast<const float4*>(&hs[r][k]);
#pragma unroll
      for (int g = 0; g < NG; g++) {
        const int jj = tid + (g << 8);
        float4 w4 = *reinterpret_cast<const float4*>(&whh[(size_t)jj * H + k]);
#pragma unroll
        for (int r = 0; r < 4; r++) acc[g][r] += dot4(w4, h4[r]);
      }
    }
#pragma unroll
    for (int g = 0; g < NG; g++) {
      const int jj = tid + (g << 8);
#pragma unroll
      for (int r = 0; r < 4; r++)
        gbuf[r][jj] = acc[g][r] + gx[((size_t)t * B_ + b0 + r) * H4 + jj];
    }
    __syncthreads();
#pragma unroll
    for (int q = 0; q < NU; q++) {
      const int u = tid + (q << 8);
      const int r = u / H, j = u % H;
      float i_ = sigf(gbuf[r][j]);
      float f_ = sigf(gbuf[r][H + j]);
      float g_ = tanhf(gbuf[r][2 * H + j]);
      float o_ = sigf(gbuf[r][3 * H + j]);
      float c2 = f_ * creg[q] + i_ * g_;
      creg[q] = c2;
      hs[r][j] = tanhf(o_ * tanhf(c2));
    }
    __syncthreads();
    if (tid < F) {
      const float* fw = fcw + (size_t)tid * H;
      float fb = fcb[tid];
      float a[4];
#pragma unroll
      for (int r = 0; r < 4; r++) a[r] = fb;
#pragma unroll 4
      for (int k = 0; k < H; k += 4) {
        float4 w4 = *reinterpret_cast<const float4*>(&fw[k]);
#pragma unroll
        for (int r = 0; r < 4; r++)
          a[r] += dot4(w4, *reinterpret_cast<const float4*>(&hs[r][k]));
      }
#pragma unroll
      for (int r = 0; r < 4; r++) {
        float um = umask[(b0 + r) * T_ + t];
        dfeat[((size_t)t * B_ + b0 + r) * 256 + COLOFF + tid] = tanhf(a[r]) * um;
      }
    }
  }
}

struct ModParams {
  const float* gx0; const float* gx1; const float* gx2;
  const float* whh0; const float* whh1; const float* whh2;
  const float* fcw0; const float* fcw1; const float* fcw2;
  const float* fcb0; const float* fcb1; const float* fcb2;
};

__global__ __launch_bounds__(256) void mod_lstm(ModParams p,
    const float* __restrict__ umask, float* __restrict__ dfeat) {
  __shared__ __align__(16) float hs[4][128];
  __shared__ __align__(16) float gbuf[4][512];
  const int mi = blockIdx.x >> 6;
  const int b0 = (blockIdx.x & 63) * 4;
  const int tid = threadIdx.x;
  if (mi == 0)      mod_body<128, 100,   0>(p.gx0, p.whh0, p.fcw0, p.fcb0, umask, dfeat, b0, tid, hs, gbuf);
  else if (mi == 1) mod_body< 64,  50, 100>(p.gx1, p.whh1, p.fcw1, p.fcb1, umask, dfeat, b0, tid, hs, gbuf);
  else              mod_body<128, 100, 150>(p.gx2, p.whh2, p.fcw2, p.fcb2, umask, dfeat, b0, tid, hs, gbuf);
}

// ---------------------------------------------------------------------------
// dlg_recur: one block per batch row, 512 threads (8 waves, <=256 VGPR).
// w_hh in fp16: 192/256 of each gate row in VGPRs (96 packed u32 x 2 rows =
// 192 regs), 64/256 in LDS (128 KB). Thread owns gate rows tid and tid+512.
// Per step: 256 x v_dot2_f32_f16 per thread against packed h (broadcast LDS
// reads), gates -> gbuf, cell update by tid<256, h -> hbuf(fp16) + hall(fp32).
// No cross-block coupling; 2 barriers/step.
// ---------------------------------------------------------------------------
#define DLG_LDS_BYTES (131072 + 4096 + 512)

__global__ __launch_bounds__(512, 2) void dlg_recur(
    const float* __restrict__ gxd, const unsigned int* __restrict__ wpk,
    const unsigned int* __restrict__ wldsg, float* __restrict__ hall) {
  extern __shared__ char smem[];
  unsigned int* wl = (unsigned int*)smem;                       // [16][1024][2]
  float* gbuf = (float*)(smem + 131072);                        // [1024]
  _Float16* hbuf_h = (_Float16*)(smem + 131072 + 4096);         // [256]
  const uint4* hbuf4 = (const uint4*)hbuf_h;                    // [32]
  const int tid = threadIdx.x;
  const int b = blockIdx.x;

  // stage LDS weight part (once)
  for (int i = tid; i < 32768; i += 512) wl[i] = wldsg[i];
  // register weight part (once): rows tid and tid+512, pairs 0..95
  unsigned int wr0[96], wr1[96];
  {
    const uint4* p0 = reinterpret_cast<const uint4*>(wpk + (size_t)tid * 96);
    const uint4* p1 = reinterpret_cast<const uint4*>(wpk + (size_t)(tid + 512) * 96);
#pragma unroll
    for (int j = 0; j < 24; j++) {
      uint4 v0 = p0[j], v1 = p1[j];
      wr0[4 * j + 0] = v0.x; wr0[4 * j + 1] = v0.y; wr0[4 * j + 2] = v0.z; wr0[4 * j + 3] = v0.w;
      wr1[4 * j + 0] = v1.x; wr1[4 * j + 1] = v1.y; wr1[4 * j + 2] = v1.z; wr1[4 * j + 3] = v1.w;
    }
  }
  if (tid < 32) reinterpret_cast<uint4*>(const_cast<_Float16*>(hbuf_h))[tid] = uint4{0, 0, 0, 0};
  float creg = 0.f;
  __syncthreads();

  const float* gbase = gxd + (size_t)b * 1024 + tid;
  float gc0 = gbase[0], gc1 = gbase[512];
  for (int t = 0; t < T_; t++) {
    float gn0 = 0.f, gn1 = 0.f;
    if (t + 1 < T_) {
      gn0 = gbase[(size_t)(t + 1) * B_ * 1024];
      gn1 = gbase[(size_t)(t + 1) * B_ * 1024 + 512];
    }
    float a0 = 0.f, a1 = 0.f;
#pragma unroll
    for (int j = 0; j < 24; j++) {                 // k pairs 0..95 (registers)
      uint4 h4 = hbuf4[j];
      a0 = fdot2f(wr0[4 * j + 0], h4.x, a0); a1 = fdot2f(wr1[4 * j + 0], h4.x, a1);
      a0 = fdot2f(wr0[4 * j + 1], h4.y, a0); a1 = fdot2f(wr1[4 * j + 1], h4.y, a1);
      a0 = fdot2f(wr0[4 * j + 2], h4.z, a0); a1 = fdot2f(wr1[4 * j + 2], h4.z, a1);
      a0 = fdot2f(wr0[4 * j + 3], h4.w, a0); a1 = fdot2f(wr1[4 * j + 3], h4.w, a1);
    }
#pragma unroll
    for (int jj = 0; jj < 8; jj++) {               // k pairs 96..127 (LDS)
      uint4 h4 = hbuf4[24 + jj];
      uint2 wa = *reinterpret_cast<const uint2*>(&wl[(2 * jj) * 2048 + 2 * tid]);
      uint2 wb = *reinterpret_cast<const uint2*>(&wl[(2 * jj + 1) * 2048 + 2 * tid]);
      uint2 wc = *reinterpret_cast<const uint2*>(&wl[(2 * jj) * 2048 + 2 * (tid + 512)]);
      uint2 wd = *reinterpret_cast<const uint2*>(&wl[(2 * jj + 1) * 2048 + 2 * (tid + 512)]);
      a0 = fdot2f(wa.x, h4.x, a0); a1 = fdot2f(wc.x, h4.x, a1);
      a0 = fdot2f(wa.y, h4.y, a0); a1 = fdot2f(wc.y, h4.y, a1);
      a0 = fdot2f(wb.x, h4.z, a0); a1 = fdot2f(wd.x, h4.z, a1);
      a0 = fdot2f(wb.y, h4.w, a0); a1 = fdot2f(wd.y, h4.w, a1);
    }
    gbuf[tid] = a0 + gc0;          // gate rows 0..511   (i, f)
    gbuf[tid + 512] = a1 + gc1;    // gate rows 512..1023 (g, o)
    __syncthreads();
    if (tid < DH_) {
      float i_ = sigf(gbuf[tid]);
      float f_ = sigf(gbuf[DH_ + tid]);
      float g_ = tanhf(gbuf[2 * DH_ + tid]);
      float o_ = sigf(gbuf[3 * DH_ + tid]);
      float c2 = f_ * creg + i_ * g_;
      creg = c2;
      float h2 = o_ * tanhf(c2);
      hall[((size_t)t * B_ + b) * DH_ + tid] = h2;
      hbuf_h[tid] = (_Float16)h2;
    }
    gc0 = gn0; gc1 = gn1;
    __syncthreads();
  }
}

// ---------------------------------------------------------------------------
// out_head: fc_out + tanh + smax + log_softmax over all 32768 (t,b) rows.
// ---------------------------------------------------------------------------
__global__ __launch_bounds__(256) void out_head(
    const float* __restrict__ hall, const float* __restrict__ fcow,
    const float* __restrict__ fcob, const float* __restrict__ smw,
    const float* __restrict__ smb, float* __restrict__ out) {
  __shared__ __align__(16) float h_lds[16][260];
  __shared__ __align__(16) float fco[16][132];
  __shared__ float lg[16][6];
  const int tid = threadIdx.x;
  const int m0 = blockIdx.x * 16;
  {
    const float* src = hall + (size_t)m0 * DH_;
    for (int e = tid; e < 1024; e += 256) {
      float4 v = reinterpret_cast<const float4*>(src)[e];
      const int r = e >> 6, k = (e & 63) * 4;
      *reinterpret_cast<float4*>(&h_lds[r][k]) = v;
    }
  }
  __syncthreads();
  {
    const int f = tid & 127, half = tid >> 7;
    float acc[8];
    const float fb = fcob[f];
#pragma unroll
    for (int r = 0; r < 8; r++) acc[r] = fb;
    const float* wrow = fcow + (size_t)f * DH_;
    for (int k = 0; k < DH_; k += 4) {
      float4 w4 = *reinterpret_cast<const float4*>(wrow + k);
#pragma unroll
      for (int r = 0; r < 8; r++)
        acc[r] += dot4(w4, *reinterpret_cast<const float4*>(&h_lds[half * 8 + r][k]));
    }
#pragma unroll
    for (int r = 0; r < 8; r++) fco[half * 8 + r][f] = tanhf(acc[r]);
  }
  __syncthreads();
  if (tid < 96) {
    const int r = tid / 6, cc = tid % 6;
    float a = smb[cc];
    const float* sw = smw + cc * 128;
#pragma unroll 4
    for (int k = 0; k < 128; k++) a += sw[k] * fco[r][k];
    lg[r][cc] = a;
  }
  __syncthreads();
  if (tid < 16) {
    const int m = m0 + tid;
    const int t = m >> 8, b = m & 255;
    float mx = lg[tid][0];
#pragma unroll
    for (int cc = 1; cc < 6; cc++) mx = fmaxf(mx, lg[tid][cc]);
    float ssum = 0.f;
#pragma unroll
    for (int cc = 0; cc < 6; cc++) ssum += __expf(lg[tid][cc] - mx);
    float lse = mx + logf(ssum);
#pragma unroll
    for (int cc = 0; cc < 6; cc++)
      out[((size_t)b * T_ + t) * 6 + cc] = lg[tid][cc] - lse;
  }
}

// ---------------------------------------------------------------------------
extern "C" void kernel_launch(void* const* d_in, const int* in_sizes, int n_in,
                              void* d_out, int out_size, void* d_ws, size_t ws_size,
                              hipStream_t stream) {
  const float* mod0  = (const float*)d_in[0];
  const float* mod1  = (const float*)d_in[1];
  const float* mod2  = (const float*)d_in[2];
  const float* umask = (const float*)d_in[3];
  const float* w_ih0 = (const float*)d_in[4];
  const float* w_hh0 = (const float*)d_in[5];
  const float* b_ih0 = (const float*)d_in[6];
  const float* b_hh0 = (const float*)d_in[7];
  const float* fc_w0 = (const float*)d_in[8];
  const float* fc_b0 = (const float*)d_in[9];
  const float* w_ih1 = (const float*)d_in[10];
  const float* w_hh1 = (const float*)d_in[11];
  const float* b_ih1 = (const float*)d_in[12];
  const float* b_hh1 = (const float*)d_in[13];
  const float* fc_w1 = (const float*)d_in[14];
  const float* fc_b1 = (const float*)d_in[15];
  const float* w_ih2 = (const float*)d_in[16];
  const float* w_hh2 = (const float*)d_in[17];
  const float* b_ih2 = (const float*)d_in[18];
  const float* b_hh2 = (const float*)d_in[19];
  const float* fc_w2 = (const float*)d_in[20];
  const float* fc_b2 = (const float*)d_in[21];
  const float* w_ih_d = (const float*)d_in[22];
  const float* w_hh_d = (const float*)d_in[23];
  const float* b_ih_d = (const float*)d_in[24];
  const float* b_hh_d = (const float*)d_in[25];
  const float* fco_w  = (const float*)d_in[26];
  const float* fco_b  = (const float*)d_in[27];
  const float* sm_w   = (const float*)d_in[28];
  const float* sm_b   = (const float*)d_in[29];

  // workspace layout (floats):
  //   [0, M*1280) : gx0|gx1|gx2 -> reused as gxd [0,M*1024) + hall [M*1024,M*1280)
  float* ws    = (float*)d_ws;
  float* gx0   = ws;                                  // M*512
  float* gx1   = gx0 + (size_t)M_ * 512;              // M*256
  float* gx2   = gx1 + (size_t)M_ * 256;              // M*512
  float* gxd   = ws;                                  // M*1024 (reuse, gx* dead)
  float* hall  = ws + (size_t)M_ * 1024;              // M*256 (reuse gx2 tail)
  float* dfeat = ws + (size_t)M_ * 1280;              // M*256 (stride 256, pad zeroed)
  float* biasd = dfeat + (size_t)M_ * 256;            // 1024
  float* bias0 = biasd + 1024;                        // 512
  float* bias1 = bias0 + 512;                         // 256
  float* bias2 = bias1 + 256;                         // 512
  float* wihd  = bias2 + 512;                         // 1024*256 padded w_ih_d
  unsigned int* wpk   = (unsigned int*)(wihd + 1024 * 256);  // 1024*96 u32
  unsigned int* wldsg = wpk + 1024 * 96;                     // 32768 u32

  prep_kernel<<<64, 256, 0, stream>>>(w_ih_d, w_hh_d, b_ih_d, b_hh_d,
      b_ih0, b_hh0, b_ih1, b_hh1, b_ih2, b_hh2,
      wihd, dfeat, biasd, bias0, bias1, bias2, wpk, wldsg);

  proj_gemm<true><<<dim3(8,  M_ / 64), 256, 0, stream>>>(mod0, w_ih0, bias0, umask, gx0, 300, 512);
  proj_gemm<true><<<dim3(4,  M_ / 64), 256, 0, stream>>>(mod1, w_ih1, bias1, umask, gx1, 100, 256);
  proj_gemm<true><<<dim3(8,  M_ / 64), 256, 0, stream>>>(mod2, w_ih2, bias2, umask, gx2, 512, 512);

  ModParams p;
  p.gx0 = gx0; p.gx1 = gx1; p.gx2 = gx2;
  p.whh0 = w_hh0; p.whh1 = w_hh1; p.whh2 = w_hh2;
  p.fcw0 = fc_w0; p.fcw1 = fc_w1; p.fcw2 = fc_w2;
  p.fcb0 = fc_b0; p.fcb1 = fc_b1; p.fcb2 = fc_b2;
  mod_lstm<<<192, 256, 0, stream>>>(p, umask, dfeat);

  // dialogue input projection: gxd = dfeat @ wihd^T + biasd (overwrites gx*)
  proj_gemm<false><<<dim3(16, M_ / 64), 256, 0, stream>>>(dfeat, wihd, biasd, nullptr, gxd, 256, 1024);

  hipFuncSetAttribute(reinterpret_cast<const void*>(dlg_recur),
                      hipFuncAttributeMaxDynamicSharedMemorySize, DLG_LDS_BYTES);
  dlg_recur<<<256, 512, DLG_LDS_BYTES, stream>>>(gxd, wpk, wldsg, hall);

  out_head<<<M_ / 16, 256, 0, stream>>>(hall, fco_w, fco_b, sm_w, sm_b, (float*)d_out);
}

// Round 5
// 1458.082 us; speedup vs baseline: 6.0020x; 1.5987x over previous
//
#include <hip/hip_runtime.h>

#define B_ 256
#define T_ 128
#define M_ (B_ * T_)
#define DH_ 256

__device__ __forceinline__ float sigf(float x) { return 1.0f / (1.0f + __expf(-x)); }
__device__ __forceinline__ float dot4(float4 a, float4 b) {
  return a.x * b.x + a.y * b.y + a.z * b.z + a.w * b.w;
}

typedef _Float16 half2v __attribute__((ext_vector_type(2)));
__device__ __forceinline__ float fdot2f(unsigned int w, unsigned int h, float acc) {
  half2v wv = __builtin_bit_cast(half2v, w);
  half2v hv = __builtin_bit_cast(half2v, h);
#if __has_builtin(__builtin_amdgcn_fdot2)
  return __builtin_amdgcn_fdot2(wv, hv, acc, false);
#else
  return acc + (float)wv[0] * (float)hv[0] + (float)wv[1] * (float)hv[1];
#endif
}
__device__ __forceinline__ unsigned int pk16(float a, float b) {
  unsigned short lo = __builtin_bit_cast(unsigned short, (_Float16)a);
  unsigned short hi = __builtin_bit_cast(unsigned short, (_Float16)b);
  return (unsigned int)lo | ((unsigned int)hi << 16);
}

// ---------------------------------------------------------------------------
// prep: combined biases, padded w_ih_d, zero dfeat pad cols, fp16-packed
// dialogue weights (reg+LDS split), and fp16-packed modality weights:
//   wpkX [4H rows][H/2 u32]  gate rows (register-resident in mod_recur)
//   fcTX [H/2 j][F r]        FC weights TRANSPOSED (LDS, conflict-free reads)
// ---------------------------------------------------------------------------
__global__ void prep_kernel(const float* __restrict__ w_ih_d, const float* __restrict__ w_hh_d,
                            const float* __restrict__ b_ih_d, const float* __restrict__ b_hh_d,
                            const float* __restrict__ b_ih0, const float* __restrict__ b_hh0,
                            const float* __restrict__ b_ih1, const float* __restrict__ b_hh1,
                            const float* __restrict__ b_ih2, const float* __restrict__ b_hh2,
                            const float* __restrict__ w_hh0, const float* __restrict__ w_hh1,
                            const float* __restrict__ w_hh2,
                            const float* __restrict__ fc_w0, const float* __restrict__ fc_w1,
                            const float* __restrict__ fc_w2,
                            float* __restrict__ wihd, float* __restrict__ dfeat,
                            float* __restrict__ biasd, float* __restrict__ bias0,
                            float* __restrict__ bias1, float* __restrict__ bias2,
                            unsigned int* __restrict__ wpk, unsigned int* __restrict__ wldsg,
                            unsigned int* __restrict__ wpk0, unsigned int* __restrict__ wpk1,
                            unsigned int* __restrict__ wpk2,
                            unsigned int* __restrict__ fcT0, unsigned int* __restrict__ fcT1,
                            unsigned int* __restrict__ fcT2) {
  int idx = blockIdx.x * blockDim.x + threadIdx.x;
  int stride = gridDim.x * blockDim.x;
  for (int i = idx; i < 1024 * 256; i += stride) {
    int j = i >> 8, k = i & 255;
    wihd[i] = (k < 250) ? w_ih_d[j * 250 + k] : 0.0f;
  }
  for (int i = idx; i < M_ * 6; i += stride)
    dfeat[(size_t)(i / 6) * 256 + 250 + (i % 6)] = 0.0f;
  // dialogue weights: reg part (pairs 0..95) + LDS part (pairs 96..127)
  for (int i = idx; i < 1024 * 96; i += stride) {
    int r = i / 96, k0 = (i % 96) * 2;
    wpk[i] = pk16(w_hh_d[(size_t)r * 256 + k0], w_hh_d[(size_t)r * 256 + k0 + 1]);
  }
  for (int i = idx; i < 32768; i += stride) {
    int j = i >> 11, rem = i & 2047, r = rem >> 1, p = rem & 1;
    int k0 = 192 + 4 * j + 2 * p;
    wldsg[i] = pk16(w_hh_d[(size_t)r * 256 + k0], w_hh_d[(size_t)r * 256 + k0 + 1]);
  }
  // modality recurrent weights (row-major packed pairs)
  for (int i = idx; i < 512 * 64; i += stride) {
    int r = i >> 6, p = (i & 63) * 2;
    wpk0[i] = pk16(w_hh0[(size_t)r * 128 + p], w_hh0[(size_t)r * 128 + p + 1]);
    wpk2[i] = pk16(w_hh2[(size_t)r * 128 + p], w_hh2[(size_t)r * 128 + p + 1]);
  }
  for (int i = idx; i < 256 * 32; i += stride) {
    int r = i >> 5, p = (i & 31) * 2;
    wpk1[i] = pk16(w_hh1[(size_t)r * 64 + p], w_hh1[(size_t)r * 64 + p + 1]);
  }
  // FC weights transposed: fcT[j*F + r] = pack(fc_w[r][2j], fc_w[r][2j+1])
  for (int i = idx; i < 64 * 100; i += stride) {
    int j = i / 100, r = i % 100;
    fcT0[i] = pk16(fc_w0[(size_t)r * 128 + 2 * j], fc_w0[(size_t)r * 128 + 2 * j + 1]);
    fcT2[i] = pk16(fc_w2[(size_t)r * 128 + 2 * j], fc_w2[(size_t)r * 128 + 2 * j + 1]);
  }
  for (int i = idx; i < 32 * 50; i += stride) {
    int j = i / 50, r = i % 50;
    fcT1[i] = pk16(fc_w1[(size_t)r * 64 + 2 * j], fc_w1[(size_t)r * 64 + 2 * j + 1]);
  }
  for (int i = idx; i < 1024; i += stride) biasd[i] = b_ih_d[i] + b_hh_d[i];
  for (int i = idx; i < 512; i += stride) bias0[i] = b_ih0[i] + b_hh0[i];
  for (int i = idx; i < 256; i += stride) bias1[i] = b_ih1[i] + b_hh1[i];
  for (int i = idx; i < 512; i += stride) bias2[i] = b_ih2[i] + b_hh2[i];
}

// ---------------------------------------------------------------------------
// proj_gemm: C[m][n] = (BTX ? umask : 1) * sum_k A[m][k]*W[n][k] + bias[n]
// ---------------------------------------------------------------------------
#define BK 16
template <bool BTX>
__global__ __launch_bounds__(256) void proj_gemm(
    const float* __restrict__ X, const float* __restrict__ W,
    const float* __restrict__ bias, const float* __restrict__ umask,
    float* __restrict__ C, int K, int N) {
  __shared__ __align__(16) float As[BK][68];
  __shared__ __align__(16) float Ws[BK][68];
  const int tid = threadIdx.x;
  const int n0 = blockIdx.x * 64;
  const int m0 = blockIdx.y * 64;
  const int t = m0 >> 8;
  const int b0 = m0 & (B_ - 1);
  const int lrow = tid >> 2, kq = tid & 3;
  const int tx = tid & 15, ty = tid >> 4;
  const float* Arow;
  if constexpr (BTX) Arow = X + ((size_t)(b0 + lrow) * T_ + t) * K;
  else               Arow = X + (size_t)(m0 + lrow) * K;
  const float* Wrow = W + (size_t)(n0 + lrow) * K;
  float acc[4][4] = {};
  for (int k0 = 0; k0 < K; k0 += BK) {
    if (k0 + BK <= K) {
      float4 av = *reinterpret_cast<const float4*>(Arow + k0 + kq * 4);
      float4 wv = *reinterpret_cast<const float4*>(Wrow + k0 + kq * 4);
      As[kq * 4 + 0][lrow] = av.x; As[kq * 4 + 1][lrow] = av.y;
      As[kq * 4 + 2][lrow] = av.z; As[kq * 4 + 3][lrow] = av.w;
      Ws[kq * 4 + 0][lrow] = wv.x; Ws[kq * 4 + 1][lrow] = wv.y;
      Ws[kq * 4 + 2][lrow] = wv.z; Ws[kq * 4 + 3][lrow] = wv.w;
    } else {
#pragma unroll
      for (int e = 0; e < 4; e++) {
        int k = k0 + kq * 4 + e;
        As[kq * 4 + e][lrow] = (k < K) ? Arow[k] : 0.0f;
        Ws[kq * 4 + e][lrow] = (k < K) ? Wrow[k] : 0.0f;
      }
    }
    __syncthreads();
#pragma unroll
    for (int kk = 0; kk < BK; kk++) {
      float4 a4 = *reinterpret_cast<const float4*>(&As[kk][ty * 4]);
      float4 w4 = *reinterpret_cast<const float4*>(&Ws[kk][tx * 4]);
      float a[4] = {a4.x, a4.y, a4.z, a4.w};
      float w[4] = {w4.x, w4.y, w4.z, w4.w};
#pragma unroll
      for (int i = 0; i < 4; i++)
#pragma unroll
        for (int j = 0; j < 4; j++) acc[i][j] += a[i] * w[j];
    }
    __syncthreads();
  }
  float4 bv = *reinterpret_cast<const float4*>(bias + n0 + tx * 4);
#pragma unroll
  for (int i = 0; i < 4; i++) {
    int m = m0 + ty * 4 + i;
    float um = 1.0f;
    if constexpr (BTX) um = umask[(b0 + ty * 4 + i) * T_ + t];
    float4 o;
    o.x = acc[i][0] * um + bv.x; o.y = acc[i][1] * um + bv.y;
    o.z = acc[i][2] * um + bv.z; o.w = acc[i][3] * um + bv.w;
    *reinterpret_cast<float4*>(C + (size_t)m * N + n0 + tx * 4) = o;
  }
}

// ---------------------------------------------------------------------------
// mod_recur: one block per (modality, batch row). Gate rows fp16 register-
// resident (H=128: 64 u32/thread, <=128 VGPR at 4 waves/EU -> 2 blocks/CU).
// FC weights fp16 in LDS transposed (consecutive-lane reads, conflict-free);
// h packed fp16 in LDS, read broadcast. 2 barriers/step. Fuses FC+tanh+umask
// into dfeat. Grid: 512 blocks (mi = blockIdx>>8 picks modality a/b) or 256.
// ---------------------------------------------------------------------------
template <int H, int F>
__global__ __launch_bounds__(4 * H, 4) void mod_recur(
    const float* __restrict__ gxa, const float* __restrict__ gxb,
    const unsigned int* __restrict__ wka, const unsigned int* __restrict__ wkb,
    const unsigned int* __restrict__ fta, const unsigned int* __restrict__ ftb,
    const float* __restrict__ fba, const float* __restrict__ fbb,
    int cola, int colb,
    const float* __restrict__ umask, float* __restrict__ dfeat) {
  constexpr int KP = H / 2;       // packed pairs per row
  constexpr int NT = 4 * H;       // threads
  __shared__ __align__(16) unsigned int fcT[KP * F];
  __shared__ __align__(16) float gbuf[4 * H];
  __shared__ __align__(16) unsigned int hbuf[KP];
  const int tid = threadIdx.x;
  const int mi = blockIdx.x >> 8;
  const int b = blockIdx.x & 255;
  const float* gx = mi ? gxb : gxa;
  const unsigned int* wk = mi ? wkb : wka;
  const unsigned int* ft = mi ? ftb : fta;
  const float* fcb = mi ? fbb : fba;
  const int col = mi ? colb : cola;

  for (int i = tid; i < KP * F; i += NT) fcT[i] = ft[i];
  unsigned int wreg[KP];
  {
    const uint4* wp = reinterpret_cast<const uint4*>(wk + (size_t)tid * KP);
#pragma unroll
    for (int j = 0; j < KP / 4; j++) {
      uint4 v = wp[j];
      wreg[4 * j + 0] = v.x; wreg[4 * j + 1] = v.y;
      wreg[4 * j + 2] = v.z; wreg[4 * j + 3] = v.w;
    }
  }
  if (tid < KP) hbuf[tid] = 0u;
  float creg = 0.f;
  __syncthreads();

  const float* gp = gx + (size_t)b * NT + tid;
  const float* ump = umask + b * T_;
  float gc = gp[0];
  const uint4* h4 = reinterpret_cast<const uint4*>(hbuf);
  for (int t = 0; t < T_; t++) {
    float gn = (t + 1 < T_) ? gp[(size_t)(t + 1) * B_ * NT] : 0.f;
    float a0 = 0.f, a1 = 0.f, a2 = 0.f, a3 = 0.f;
#pragma unroll
    for (int j = 0; j < KP / 4; j++) {
      uint4 hv = h4[j];
      a0 = fdot2f(wreg[4 * j + 0], hv.x, a0);
      a1 = fdot2f(wreg[4 * j + 1], hv.y, a1);
      a2 = fdot2f(wreg[4 * j + 2], hv.z, a2);
      a3 = fdot2f(wreg[4 * j + 3], hv.w, a3);
    }
    gbuf[tid] = (a0 + a1) + (a2 + a3) + gc;   // gx includes bias (+umask'd x)
    gc = gn;
    __syncthreads();                          // S1: gates ready
    if (tid < H) {
      float i_ = sigf(gbuf[tid]);
      float f_ = sigf(gbuf[H + tid]);
      float g_ = tanhf(gbuf[2 * H + tid]);
      float o_ = sigf(gbuf[3 * H + tid]);
      float c2 = f_ * creg + i_ * g_;
      creg = c2;
      float h2 = tanhf(o_ * tanhf(c2));       // extra tanh on hidden state
      float hp = __shfl_xor(h2, 1);
      if ((tid & 1) == 0) hbuf[tid >> 1] = pk16(h2, hp);
    }
    __syncthreads();                          // S2: h_t packed in hbuf
    if (tid < F) {
      float fa = fcb[tid];
#pragma unroll
      for (int j4 = 0; j4 < KP / 4; j4++) {
        uint4 hv = h4[j4];
        fa = fdot2f(fcT[(4 * j4 + 0) * F + tid], hv.x, fa);
        fa = fdot2f(fcT[(4 * j4 + 1) * F + tid], hv.y, fa);
        fa = fdot2f(fcT[(4 * j4 + 2) * F + tid], hv.z, fa);
        fa = fdot2f(fcT[(4 * j4 + 3) * F + tid], hv.w, fa);
      }
      dfeat[((size_t)t * B_ + b) * 256 + col + tid] = tanhf(fa) * ump[t];
    }
    // no barrier: next gate phase only reads hbuf; next hbuf write is after S1
  }
}

// ---------------------------------------------------------------------------
// dlg_recur: unchanged from round 4 (verified fast).
// ---------------------------------------------------------------------------
#define DLG_LDS_BYTES (131072 + 4096 + 512)

__global__ __launch_bounds__(512, 2) void dlg_recur(
    const float* __restrict__ gxd, const unsigned int* __restrict__ wpk,
    const unsigned int* __restrict__ wldsg, float* __restrict__ hall) {
  extern __shared__ char smem[];
  unsigned int* wl = (unsigned int*)smem;                       // [16][1024][2]
  float* gbuf = (float*)(smem + 131072);                        // [1024]
  _Float16* hbuf_h = (_Float16*)(smem + 131072 + 4096);         // [256]
  const uint4* hbuf4 = (const uint4*)hbuf_h;                    // [32]
  const int tid = threadIdx.x;
  const int b = blockIdx.x;

  for (int i = tid; i < 32768; i += 512) wl[i] = wldsg[i];
  unsigned int wr0[96], wr1[96];
  {
    const uint4* p0 = reinterpret_cast<const uint4*>(wpk + (size_t)tid * 96);
    const uint4* p1 = reinterpret_cast<const uint4*>(wpk + (size_t)(tid + 512) * 96);
#pragma unroll
    for (int j = 0; j < 24; j++) {
      uint4 v0 = p0[j], v1 = p1[j];
      wr0[4 * j + 0] = v0.x; wr0[4 * j + 1] = v0.y; wr0[4 * j + 2] = v0.z; wr0[4 * j + 3] = v0.w;
      wr1[4 * j + 0] = v1.x; wr1[4 * j + 1] = v1.y; wr1[4 * j + 2] = v1.z; wr1[4 * j + 3] = v1.w;
    }
  }
  if (tid < 32) reinterpret_cast<uint4*>(const_cast<_Float16*>(hbuf_h))[tid] = uint4{0, 0, 0, 0};
  float creg = 0.f;
  __syncthreads();

  const float* gbase = gxd + (size_t)b * 1024 + tid;
  float gc0 = gbase[0], gc1 = gbase[512];
  for (int t = 0; t < T_; t++) {
    float gn0 = 0.f, gn1 = 0.f;
    if (t + 1 < T_) {
      gn0 = gbase[(size_t)(t + 1) * B_ * 1024];
      gn1 = gbase[(size_t)(t + 1) * B_ * 1024 + 512];
    }
    float a0 = 0.f, a1 = 0.f;
#pragma unroll
    for (int j = 0; j < 24; j++) {
      uint4 hv = hbuf4[j];
      a0 = fdot2f(wr0[4 * j + 0], hv.x, a0); a1 = fdot2f(wr1[4 * j + 0], hv.x, a1);
      a0 = fdot2f(wr0[4 * j + 1], hv.y, a0); a1 = fdot2f(wr1[4 * j + 1], hv.y, a1);
      a0 = fdot2f(wr0[4 * j + 2], hv.z, a0); a1 = fdot2f(wr1[4 * j + 2], hv.z, a1);
      a0 = fdot2f(wr0[4 * j + 3], hv.w, a0); a1 = fdot2f(wr1[4 * j + 3], hv.w, a1);
    }
#pragma unroll
    for (int jj = 0; jj < 8; jj++) {
      uint4 hv = hbuf4[24 + jj];
      uint2 wa = *reinterpret_cast<const uint2*>(&wl[(2 * jj) * 2048 + 2 * tid]);
      uint2 wb = *reinterpret_cast<const uint2*>(&wl[(2 * jj + 1) * 2048 + 2 * tid]);
      uint2 wc = *reinterpret_cast<const uint2*>(&wl[(2 * jj) * 2048 + 2 * (tid + 512)]);
      uint2 wd = *reinterpret_cast<const uint2*>(&wl[(2 * jj + 1) * 2048 + 2 * (tid + 512)]);
      a0 = fdot2f(wa.x, hv.x, a0); a1 = fdot2f(wc.x, hv.x, a1);
      a0 = fdot2f(wa.y, hv.y, a0); a1 = fdot2f(wc.y, hv.y, a1);
      a0 = fdot2f(wb.x, hv.z, a0); a1 = fdot2f(wd.x, hv.z, a1);
      a0 = fdot2f(wb.y, hv.w, a0); a1 = fdot2f(wd.y, hv.w, a1);
    }
    gbuf[tid] = a0 + gc0;
    gbuf[tid + 512] = a1 + gc1;
    __syncthreads();
    if (tid < DH_) {
      float i_ = sigf(gbuf[tid]);
      float f_ = sigf(gbuf[DH_ + tid]);
      float g_ = tanhf(gbuf[2 * DH_ + tid]);
      float o_ = sigf(gbuf[3 * DH_ + tid]);
      float c2 = f_ * creg + i_ * g_;
      creg = c2;
      float h2 = o_ * tanhf(c2);
      hall[((size_t)t * B_ + b) * DH_ + tid] = h2;
      hbuf_h[tid] = (_Float16)h2;
    }
    gc0 = gn0; gc1 = gn1;
    __syncthreads();
  }
}

// ---------------------------------------------------------------------------
// out_head: fc_out + tanh + smax + log_softmax over all 32768 (t,b) rows.
// ---------------------------------------------------------------------------
__global__ __launch_bounds__(256) void out_head(
    const float* __restrict__ hall, const float* __restrict__ fcow,
    const float* __restrict__ fcob, const float* __restrict__ smw,
    const float* __restrict__ smb, float* __restrict__ out) {
  __shared__ __align__(16) float h_lds[16][260];
  __shared__ __align__(16) float fco[16][132];
  __shared__ float lg[16][6];
  const int tid = threadIdx.x;
  const int m0 = blockIdx.x * 16;
  {
    const float* src = hall + (size_t)m0 * DH_;
    for (int e = tid; e < 1024; e += 256) {
      float4 v = reinterpret_cast<const float4*>(src)[e];
      const int r = e >> 6, k = (e & 63) * 4;
      *reinterpret_cast<float4*>(&h_lds[r][k]) = v;
    }
  }
  __syncthreads();
  {
    const int f = tid & 127, half = tid >> 7;
    float acc[8];
    const float fb = fcob[f];
#pragma unroll
    for (int r = 0; r < 8; r++) acc[r] = fb;
    const float* wrow = fcow + (size_t)f * DH_;
    for (int k = 0; k < DH_; k += 4) {
      float4 w4 = *reinterpret_cast<const float4*>(wrow + k);
#pragma unroll
      for (int r = 0; r < 8; r++)
        acc[r] += dot4(w4, *reinterpret_cast<const float4*>(&h_lds[half * 8 + r][k]));
    }
#pragma unroll
    for (int r = 0; r < 8; r++) fco[half * 8 + r][f] = tanhf(acc[r]);
  }
  __syncthreads();
  if (tid < 96) {
    const int r = tid / 6, cc = tid % 6;
    float a = smb[cc];
    const float* sw = smw + cc * 128;
#pragma unroll 4
    for (int k = 0; k < 128; k++) a += sw[k] * fco[r][k];
    lg[r][cc] = a;
  }
  __syncthreads();
  if (tid < 16) {
    const int m = m0 + tid;
    const int t = m >> 8, b = m & 255;
    float mx = lg[tid][0];
#pragma unroll
    for (int cc = 1; cc < 6; cc++) mx = fmaxf(mx, lg[tid][cc]);
    float ssum = 0.f;
#pragma unroll
    for (int cc = 0; cc < 6; cc++) ssum += __expf(lg[tid][cc] - mx);
    float lse = mx + logf(ssum);
#pragma unroll
    for (int cc = 0; cc < 6; cc++)
      out[((size_t)b * T_ + t) * 6 + cc] = lg[tid][cc] - lse;
  }
}

// ---------------------------------------------------------------------------
extern "C" void kernel_launch(void* const* d_in, const int* in_sizes, int n_in,
                              void* d_out, int out_size, void* d_ws, size_t ws_size,
                              hipStream_t stream) {
  const float* mod0  = (const float*)d_in[0];
  const float* mod1  = (const float*)d_in[1];
  const float* mod2  = (const float*)d_in[2];
  const float* umask = (const float*)d_in[3];
  const float* w_ih0 = (const float*)d_in[4];
  const float* w_hh0 = (const float*)d_in[5];
  const float* b_ih0 = (const float*)d_in[6];
  const float* b_hh0 = (const float*)d_in[7];
  const float* fc_w0 = (const float*)d_in[8];
  const float* fc_b0 = (const float*)d_in[9];
  const float* w_ih1 = (const float*)d_in[10];
  const float* w_hh1 = (const float*)d_in[11];
  const float* b_ih1 = (const float*)d_in[12];
  const float* b_hh1 = (const float*)d_in[13];
  const float* fc_w1 = (const float*)d_in[14];
  const float* fc_b1 = (const float*)d_in[15];
  const float* w_ih2 = (const float*)d_in[16];
  const float* w_hh2 = (const float*)d_in[17];
  const float* b_ih2 = (const float*)d_in[18];
  const float* b_hh2 = (const float*)d_in[19];
  const float* fc_w2 = (const float*)d_in[20];
  const float* fc_b2 = (const float*)d_in[21];
  const float* w_ih_d = (const float*)d_in[22];
  const float* w_hh_d = (const float*)d_in[23];
  const float* b_ih_d = (const float*)d_in[24];
  const float* b_hh_d = (const float*)d_in[25];
  const float* fco_w  = (const float*)d_in[26];
  const float* fco_b  = (const float*)d_in[27];
  const float* sm_w   = (const float*)d_in[28];
  const float* sm_b   = (const float*)d_in[29];

  // workspace layout (floats):
  //   [0, M*1280) : gx0|gx1|gx2 -> reused as gxd [0,M*1024) + hall [M*1024,M*1280)
  float* ws    = (float*)d_ws;
  float* gx0   = ws;                                  // M*512
  float* gx1   = gx0 + (size_t)M_ * 512;              // M*256
  float* gx2   = gx1 + (size_t)M_ * 256;              // M*512
  float* gxd   = ws;                                  // M*1024 (reuse, gx* dead)
  float* hall  = ws + (size_t)M_ * 1024;              // M*256 (reuse gx2 tail)
  float* dfeat = ws + (size_t)M_ * 1280;              // M*256 (stride 256, pad zeroed)
  float* biasd = dfeat + (size_t)M_ * 256;            // 1024
  float* bias0 = biasd + 1024;                        // 512
  float* bias1 = bias0 + 512;                         // 256
  float* bias2 = bias1 + 256;                         // 512
  float* wihd  = bias2 + 512;                         // 1024*256 padded w_ih_d
  unsigned int* wpk   = (unsigned int*)(wihd + 1024 * 256);  // 1024*96 u32
  unsigned int* wldsg = wpk + 1024 * 96;                     // 32768 u32
  unsigned int* wpk0  = wldsg + 32768;                       // 512*64
  unsigned int* wpk1  = wpk0 + 512 * 64;                     // 256*32
  unsigned int* wpk2  = wpk1 + 256 * 32;                     // 512*64
  unsigned int* fcT0  = wpk2 + 512 * 64;                     // 64*100
  unsigned int* fcT1  = fcT0 + 64 * 100;                     // 32*50
  unsigned int* fcT2  = fcT1 + 32 * 50;                      // 64*100

  prep_kernel<<<128, 256, 0, stream>>>(w_ih_d, w_hh_d, b_ih_d, b_hh_d,
      b_ih0, b_hh0, b_ih1, b_hh1, b_ih2, b_hh2,
      w_hh0, w_hh1, w_hh2, fc_w0, fc_w1, fc_w2,
      wihd, dfeat, biasd, bias0, bias1, bias2, wpk, wldsg,
      wpk0, wpk1, wpk2, fcT0, fcT1, fcT2);

  proj_gemm<true><<<dim3(8,  M_ / 64), 256, 0, stream>>>(mod0, w_ih0, bias0, umask, gx0, 300, 512);
  proj_gemm<true><<<dim3(4,  M_ / 64), 256, 0, stream>>>(mod1, w_ih1, bias1, umask, gx1, 100, 256);
  proj_gemm<true><<<dim3(8,  M_ / 64), 256, 0, stream>>>(mod2, w_ih2, bias2, umask, gx2, 512, 512);

  // modality scans: mod0+mod2 in one launch (H=128), mod1 separate (H=64)
  mod_recur<128, 100><<<512, 512, 0, stream>>>(
      gx0, gx2, wpk0, wpk2, fcT0, fcT2, fc_b0, fc_b2, 0, 150, umask, dfeat);
  mod_recur<64, 50><<<256, 256, 0, stream>>>(
      gx1, gx1, wpk1, wpk1, fcT1, fcT1, fc_b1, fc_b1, 100, 100, umask, dfeat);

  // dialogue input projection: gxd = dfeat @ wihd^T + biasd (overwrites gx*)
  proj_gemm<false><<<dim3(16, M_ / 64), 256, 0, stream>>>(dfeat, wihd, biasd, nullptr, gxd, 256, 1024);

  hipFuncSetAttribute(reinterpret_cast<const void*>(dlg_recur),
                      hipFuncAttributeMaxDynamicSharedMemorySize, DLG_LDS_BYTES);
  dlg_recur<<<256, 512, DLG_LDS_BYTES, stream>>>(gxd, wpk, wldsg, hall);

  out_head<<<M_ / 16, 256, 0, stream>>>(hall, fco_w, fco_b, sm_w, sm_b, (float*)d_out);
}

// Round 6
// 1030.312 us; speedup vs baseline: 8.4939x; 1.4152x over previous
//
#include <hip/hip_runtime.h>

#define B_ 256
#define T_ 128
#define M_ (B_ * T_)
#define DH_ 256

__device__ __forceinline__ float sigf(float x) { return 1.0f / (1.0f + __expf(-x)); }
__device__ __forceinline__ float dot4(float4 a, float4 b) {
  return a.x * b.x + a.y * b.y + a.z * b.z + a.w * b.w;
}

typedef _Float16 half2v __attribute__((ext_vector_type(2)));
typedef short short8 __attribute__((ext_vector_type(8)));
typedef float f32x4 __attribute__((ext_vector_type(4)));

__device__ __forceinline__ float fdot2f(unsigned int w, unsigned int h, float acc) {
  half2v wv = __builtin_bit_cast(half2v, w);
  half2v hv = __builtin_bit_cast(half2v, h);
#if __has_builtin(__builtin_amdgcn_fdot2)
  return __builtin_amdgcn_fdot2(wv, hv, acc, false);
#else
  return acc + (float)wv[0] * (float)hv[0] + (float)wv[1] * (float)hv[1];
#endif
}
__device__ __forceinline__ unsigned int pk16(float a, float b) {
  unsigned short lo = __builtin_bit_cast(unsigned short, (_Float16)a);
  unsigned short hi = __builtin_bit_cast(unsigned short, (_Float16)b);
  return (unsigned int)lo | ((unsigned int)hi << 16);
}
__device__ __forceinline__ unsigned short bf16c(float x) {  // RNE f32->bf16
  unsigned int u = __builtin_bit_cast(unsigned int, x);
  return (unsigned short)((u + 0x7FFFu + ((u >> 16) & 1u)) >> 16);
}
__device__ __forceinline__ unsigned int bfpk(float a, float b) {
  return (unsigned int)bf16c(a) | ((unsigned int)bf16c(b) << 16);
}

// ---------------------------------------------------------------------------
// prep: combined biases; fp16-packed recurrent weights (dialogue reg/LDS
// split + modality reg + FC transposed); bf16 zero-padded GEMM weights
// (w0b[512][320], w1b[256][128], w2b[512][512], wdb[1024][256]); zero the
// bf16 dfeat pad columns.
// ---------------------------------------------------------------------------
__global__ void prep_kernel(const float* __restrict__ w_ih_d, const float* __restrict__ w_hh_d,
                            const float* __restrict__ b_ih_d, const float* __restrict__ b_hh_d,
                            const float* __restrict__ b_ih0, const float* __restrict__ b_hh0,
                            const float* __restrict__ b_ih1, const float* __restrict__ b_hh1,
                            const float* __restrict__ b_ih2, const float* __restrict__ b_hh2,
                            const float* __restrict__ w_hh0, const float* __restrict__ w_hh1,
                            const float* __restrict__ w_hh2,
                            const float* __restrict__ w_ih0, const float* __restrict__ w_ih1,
                            const float* __restrict__ w_ih2,
                            const float* __restrict__ fc_w0, const float* __restrict__ fc_w1,
                            const float* __restrict__ fc_w2,
                            unsigned short* __restrict__ dfeat_h,
                            float* __restrict__ biasd, float* __restrict__ bias0,
                            float* __restrict__ bias1, float* __restrict__ bias2,
                            unsigned int* __restrict__ wpk, unsigned int* __restrict__ wldsg,
                            unsigned int* __restrict__ wpk0, unsigned int* __restrict__ wpk1,
                            unsigned int* __restrict__ wpk2,
                            unsigned int* __restrict__ fcT0, unsigned int* __restrict__ fcT1,
                            unsigned int* __restrict__ fcT2,
                            unsigned short* __restrict__ w0b, unsigned short* __restrict__ w1b,
                            unsigned short* __restrict__ w2b, unsigned short* __restrict__ wdb) {
  int idx = blockIdx.x * blockDim.x + threadIdx.x;
  int stride = gridDim.x * blockDim.x;
  // bf16 GEMM weights (K zero-padded to multiple of 32)
  for (int i = idx; i < 512 * 320; i += stride) {
    int r = i / 320, k = i % 320;
    w0b[i] = (k < 300) ? bf16c(w_ih0[(size_t)r * 300 + k]) : (unsigned short)0;
  }
  for (int i = idx; i < 256 * 128; i += stride) {
    int r = i >> 7, k = i & 127;
    w1b[i] = (k < 100) ? bf16c(w_ih1[(size_t)r * 100 + k]) : (unsigned short)0;
  }
  for (int i = idx; i < 512 * 512; i += stride) w2b[i] = bf16c(w_ih2[i]);
  for (int i = idx; i < 1024 * 256; i += stride) {
    int r = i >> 8, k = i & 255;
    wdb[i] = (k < 250) ? bf16c(w_ih_d[(size_t)r * 250 + k]) : (unsigned short)0;
  }
  for (int i = idx; i < M_ * 6; i += stride)   // zero dfeat_h pad cols 250..255
    dfeat_h[(size_t)(i / 6) * 256 + 250 + (i % 6)] = 0;
  // dialogue recurrent weights fp16: reg part (pairs 0..95) + LDS part
  for (int i = idx; i < 1024 * 96; i += stride) {
    int r = i / 96, k0 = (i % 96) * 2;
    wpk[i] = pk16(w_hh_d[(size_t)r * 256 + k0], w_hh_d[(size_t)r * 256 + k0 + 1]);
  }
  for (int i = idx; i < 32768; i += stride) {
    int j = i >> 11, rem = i & 2047, r = rem >> 1, p = rem & 1;
    int k0 = 192 + 4 * j + 2 * p;
    wldsg[i] = pk16(w_hh_d[(size_t)r * 256 + k0], w_hh_d[(size_t)r * 256 + k0 + 1]);
  }
  // modality recurrent weights fp16 (row-major packed pairs)
  for (int i = idx; i < 512 * 64; i += stride) {
    int r = i >> 6, p = (i & 63) * 2;
    wpk0[i] = pk16(w_hh0[(size_t)r * 128 + p], w_hh0[(size_t)r * 128 + p + 1]);
    wpk2[i] = pk16(w_hh2[(size_t)r * 128 + p], w_hh2[(size_t)r * 128 + p + 1]);
  }
  for (int i = idx; i < 256 * 32; i += stride) {
    int r = i >> 5, p = (i & 31) * 2;
    wpk1[i] = pk16(w_hh1[(size_t)r * 64 + p], w_hh1[(size_t)r * 64 + p + 1]);
  }
  // FC weights fp16 transposed
  for (int i = idx; i < 64 * 100; i += stride) {
    int j = i / 100, r = i % 100;
    fcT0[i] = pk16(fc_w0[(size_t)r * 128 + 2 * j], fc_w0[(size_t)r * 128 + 2 * j + 1]);
    fcT2[i] = pk16(fc_w2[(size_t)r * 128 + 2 * j], fc_w2[(size_t)r * 128 + 2 * j + 1]);
  }
  for (int i = idx; i < 32 * 50; i += stride) {
    int j = i / 50, r = i % 50;
    fcT1[i] = pk16(fc_w1[(size_t)r * 64 + 2 * j], fc_w1[(size_t)r * 64 + 2 * j + 1]);
  }
  for (int i = idx; i < 1024; i += stride) biasd[i] = b_ih_d[i] + b_hh_d[i];
  for (int i = idx; i < 512; i += stride) bias0[i] = b_ih0[i] + b_hh0[i];
  for (int i = idx; i < 256; i += stride) bias1[i] = b_ih1[i] + b_hh1[i];
  for (int i = idx; i < 512; i += stride) bias2[i] = b_ih2[i] + b_hh2[i];
}

// ---------------------------------------------------------------------------
// mfma_gemm: C[m][n] = scale * sum_k X[m][k]*W[n][k] + bias[n], bf16 MFMA.
// 64x64 tile, 256 thr / 4 waves, wave = 16x64 slab (1 A-frag, 4 B-frags,
// 4x mfma_f32_16x16x32_bf16 per K-step). W is bf16 [N][Kp], Kp%32==0,
// zero-padded (no B guards). XF16=false: X fp32 [B,T,K] (m=t*B+b), converted
// to bf16 in staging regs, scale=umask[b][t]. XF16=true: X bf16 [M][Kp].
// 1D grid with XCD-chunked decode: all n-tiles of an m-tile on one XCD.
// ---------------------------------------------------------------------------
template <bool XF16>
__global__ __launch_bounds__(256) void mfma_gemm(
    const void* __restrict__ Xv, const unsigned short* __restrict__ Wb,
    const float* __restrict__ bias, const float* __restrict__ umask,
    float* __restrict__ C, int K, int Kp, int N) {
  __shared__ __align__(16) unsigned short Xs[64][40];  // stride 40: 2-way max conflict
  __shared__ __align__(16) unsigned short Ws[64][40];
  const int tid = threadIdx.x;
  const int d = blockIdx.x;
  const int nx = N >> 6;
  const int n0 = ((d % (nx << 3)) >> 3) << 6;
  const int m0 = (((d / (nx << 3)) << 3) + (d & 7)) << 6;
  const int srow = tid >> 2, kq = tid & 3;          // staging: row, k-quad
  const int w = tid >> 6, lane = tid & 63;          // mfma: wave, lane
  const int lr = lane & 15, lk = lane >> 4;
  const float* Xf = nullptr;
  const unsigned short* Xh = nullptr;
  if constexpr (XF16) {
    Xh = (const unsigned short*)Xv + (size_t)(m0 + srow) * Kp;
  } else {
    const int t = m0 >> 8, b0 = m0 & 255;
    Xf = (const float*)Xv + ((size_t)(b0 + srow) * T_ + t) * K;
  }
  const unsigned short* Wr = Wb + (size_t)(n0 + srow) * Kp;
  f32x4 acc[4];
#pragma unroll
  for (int j = 0; j < 4; j++) acc[j] = (f32x4){0.f, 0.f, 0.f, 0.f};

  for (int k0 = 0; k0 < Kp; k0 += 32) {
    uint4 xa;
    const int kk = k0 + kq * 8;
    if constexpr (XF16) {
      xa = *reinterpret_cast<const uint4*>(Xh + kk);
    } else {
      float4 va = (kk + 3 < K) ? *reinterpret_cast<const float4*>(Xf + kk)
                               : make_float4(0.f, 0.f, 0.f, 0.f);
      float4 vb = (kk + 7 < K) ? *reinterpret_cast<const float4*>(Xf + kk + 4)
                               : make_float4(0.f, 0.f, 0.f, 0.f);
      xa.x = bfpk(va.x, va.y); xa.y = bfpk(va.z, va.w);
      xa.z = bfpk(vb.x, vb.y); xa.w = bfpk(vb.z, vb.w);
    }
    uint4 wv = *reinterpret_cast<const uint4*>(Wr + kk);
    __syncthreads();  // previous tile's MFMA reads done
    *reinterpret_cast<uint4*>(&Xs[srow][kq * 8]) = xa;
    *reinterpret_cast<uint4*>(&Ws[srow][kq * 8]) = wv;
    __syncthreads();  // tiles staged
    short8 af = *reinterpret_cast<const short8*>(&Xs[w * 16 + lr][lk * 8]);
#pragma unroll
    for (int j = 0; j < 4; j++) {
      short8 bf = *reinterpret_cast<const short8*>(&Ws[j * 16 + lr][lk * 8]);
      acc[j] = __builtin_amdgcn_mfma_f32_16x16x32_bf16(af, bf, acc[j], 0, 0, 0);
    }
  }
  // epilogue: C/D map col=lane&15, row=(lane>>4)*4+reg
#pragma unroll
  for (int j = 0; j < 4; j++) {
    const int col = n0 + j * 16 + lr;
    const float bv = bias[col];
#pragma unroll
    for (int r = 0; r < 4; r++) {
      const int mrow = m0 + w * 16 + lk * 4 + r;
      float um = 1.0f;
      if constexpr (!XF16)
        um = umask[((m0 & 255) + w * 16 + lk * 4 + r) * T_ + (m0 >> 8)];
      C[(size_t)mrow * N + col] = acc[j][r] * um + bv;
    }
  }
}

// ---------------------------------------------------------------------------
// mod_recur: one block per (modality, batch row); fp16 register-resident
// gate rows; FC fp16 transposed in LDS; h packed fp16 in LDS. Writes dfeat
// as bf16 (GEMM consumes it). Unchanged otherwise from round 5.
// ---------------------------------------------------------------------------
template <int H, int F>
__global__ __launch_bounds__(4 * H, 4) void mod_recur(
    const float* __restrict__ gxa, const float* __restrict__ gxb,
    const unsigned int* __restrict__ wka, const unsigned int* __restrict__ wkb,
    const unsigned int* __restrict__ fta, const unsigned int* __restrict__ ftb,
    const float* __restrict__ fba, const float* __restrict__ fbb,
    int cola, int colb,
    const float* __restrict__ umask, unsigned short* __restrict__ dfeat_h) {
  constexpr int KP = H / 2;
  constexpr int NT = 4 * H;
  __shared__ __align__(16) unsigned int fcT[KP * F];
  __shared__ __align__(16) float gbuf[4 * H];
  __shared__ __align__(16) unsigned int hbuf[KP];
  const int tid = threadIdx.x;
  const int mi = blockIdx.x >> 8;
  const int b = blockIdx.x & 255;
  const float* gx = mi ? gxb : gxa;
  const unsigned int* wk = mi ? wkb : wka;
  const unsigned int* ft = mi ? ftb : fta;
  const float* fcb = mi ? fbb : fba;
  const int col = mi ? colb : cola;

  for (int i = tid; i < KP * F; i += NT) fcT[i] = ft[i];
  unsigned int wreg[KP];
  {
    const uint4* wp = reinterpret_cast<const uint4*>(wk + (size_t)tid * KP);
#pragma unroll
    for (int j = 0; j < KP / 4; j++) {
      uint4 v = wp[j];
      wreg[4 * j + 0] = v.x; wreg[4 * j + 1] = v.y;
      wreg[4 * j + 2] = v.z; wreg[4 * j + 3] = v.w;
    }
  }
  if (tid < KP) hbuf[tid] = 0u;
  float creg = 0.f;
  __syncthreads();

  const float* gp = gx + (size_t)b * NT + tid;
  const float* ump = umask + b * T_;
  float gc = gp[0];
  const uint4* h4 = reinterpret_cast<const uint4*>(hbuf);
  for (int t = 0; t < T_; t++) {
    float gn = (t + 1 < T_) ? gp[(size_t)(t + 1) * B_ * NT] : 0.f;
    float a0 = 0.f, a1 = 0.f, a2 = 0.f, a3 = 0.f;
#pragma unroll
    for (int j = 0; j < KP / 4; j++) {
      uint4 hv = h4[j];
      a0 = fdot2f(wreg[4 * j + 0], hv.x, a0);
      a1 = fdot2f(wreg[4 * j + 1], hv.y, a1);
      a2 = fdot2f(wreg[4 * j + 2], hv.z, a2);
      a3 = fdot2f(wreg[4 * j + 3], hv.w, a3);
    }
    gbuf[tid] = (a0 + a1) + (a2 + a3) + gc;
    gc = gn;
    __syncthreads();
    if (tid < H) {
      float i_ = sigf(gbuf[tid]);
      float f_ = sigf(gbuf[H + tid]);
      float g_ = tanhf(gbuf[2 * H + tid]);
      float o_ = sigf(gbuf[3 * H + tid]);
      float c2 = f_ * creg + i_ * g_;
      creg = c2;
      float h2 = tanhf(o_ * tanhf(c2));
      float hp = __shfl_xor(h2, 1);
      if ((tid & 1) == 0) hbuf[tid >> 1] = pk16(h2, hp);
    }
    __syncthreads();
    if (tid < F) {
      float fa = fcb[tid];
#pragma unroll
      for (int j4 = 0; j4 < KP / 4; j4++) {
        uint4 hv = h4[j4];
        fa = fdot2f(fcT[(4 * j4 + 0) * F + tid], hv.x, fa);
        fa = fdot2f(fcT[(4 * j4 + 1) * F + tid], hv.y, fa);
        fa = fdot2f(fcT[(4 * j4 + 2) * F + tid], hv.z, fa);
        fa = fdot2f(fcT[(4 * j4 + 3) * F + tid], hv.w, fa);
      }
      dfeat_h[((size_t)t * B_ + b) * 256 + col + tid] = bf16c(tanhf(fa) * ump[t]);
    }
  }
}

// ---------------------------------------------------------------------------
// dlg_recur: unchanged (reads gxd fp32; fp16 reg/LDS-split weights).
// ---------------------------------------------------------------------------
#define DLG_LDS_BYTES (131072 + 4096 + 512)

__global__ __launch_bounds__(512, 2) void dlg_recur(
    const float* __restrict__ gxd, const unsigned int* __restrict__ wpk,
    const unsigned int* __restrict__ wldsg, float* __restrict__ hall) {
  extern __shared__ char smem[];
  unsigned int* wl = (unsigned int*)smem;
  float* gbuf = (float*)(smem + 131072);
  _Float16* hbuf_h = (_Float16*)(smem + 131072 + 4096);
  const uint4* hbuf4 = (const uint4*)hbuf_h;
  const int tid = threadIdx.x;
  const int b = blockIdx.x;

  for (int i = tid; i < 32768; i += 512) wl[i] = wldsg[i];
  unsigned int wr0[96], wr1[96];
  {
    const uint4* p0 = reinterpret_cast<const uint4*>(wpk + (size_t)tid * 96);
    const uint4* p1 = reinterpret_cast<const uint4*>(wpk + (size_t)(tid + 512) * 96);
#pragma unroll
    for (int j = 0; j < 24; j++) {
      uint4 v0 = p0[j], v1 = p1[j];
      wr0[4 * j + 0] = v0.x; wr0[4 * j + 1] = v0.y; wr0[4 * j + 2] = v0.z; wr0[4 * j + 3] = v0.w;
      wr1[4 * j + 0] = v1.x; wr1[4 * j + 1] = v1.y; wr1[4 * j + 2] = v1.z; wr1[4 * j + 3] = v1.w;
    }
  }
  if (tid < 32) reinterpret_cast<uint4*>(const_cast<_Float16*>(hbuf_h))[tid] = uint4{0, 0, 0, 0};
  float creg = 0.f;
  __syncthreads();

  const float* gbase = gxd + (size_t)b * 1024 + tid;
  float gc0 = gbase[0], gc1 = gbase[512];
  for (int t = 0; t < T_; t++) {
    float gn0 = 0.f, gn1 = 0.f;
    if (t + 1 < T_) {
      gn0 = gbase[(size_t)(t + 1) * B_ * 1024];
      gn1 = gbase[(size_t)(t + 1) * B_ * 1024 + 512];
    }
    float a0 = 0.f, a1 = 0.f;
#pragma unroll
    for (int j = 0; j < 24; j++) {
      uint4 hv = hbuf4[j];
      a0 = fdot2f(wr0[4 * j + 0], hv.x, a0); a1 = fdot2f(wr1[4 * j + 0], hv.x, a1);
      a0 = fdot2f(wr0[4 * j + 1], hv.y, a0); a1 = fdot2f(wr1[4 * j + 1], hv.y, a1);
      a0 = fdot2f(wr0[4 * j + 2], hv.z, a0); a1 = fdot2f(wr1[4 * j + 2], hv.z, a1);
      a0 = fdot2f(wr0[4 * j + 3], hv.w, a0); a1 = fdot2f(wr1[4 * j + 3], hv.w, a1);
    }
#pragma unroll
    for (int jj = 0; jj < 8; jj++) {
      uint4 hv = hbuf4[24 + jj];
      uint2 wa = *reinterpret_cast<const uint2*>(&wl[(2 * jj) * 2048 + 2 * tid]);
      uint2 wb = *reinterpret_cast<const uint2*>(&wl[(2 * jj + 1) * 2048 + 2 * tid]);
      uint2 wc = *reinterpret_cast<const uint2*>(&wl[(2 * jj) * 2048 + 2 * (tid + 512)]);
      uint2 wd = *reinterpret_cast<const uint2*>(&wl[(2 * jj + 1) * 2048 + 2 * (tid + 512)]);
      a0 = fdot2f(wa.x, hv.x, a0); a1 = fdot2f(wc.x, hv.x, a1);
      a0 = fdot2f(wa.y, hv.y, a0); a1 = fdot2f(wc.y, hv.y, a1);
      a0 = fdot2f(wb.x, hv.z, a0); a1 = fdot2f(wd.x, hv.z, a1);
      a0 = fdot2f(wb.y, hv.w, a0); a1 = fdot2f(wd.y, hv.w, a1);
    }
    gbuf[tid] = a0 + gc0;
    gbuf[tid + 512] = a1 + gc1;
    __syncthreads();
    if (tid < DH_) {
      float i_ = sigf(gbuf[tid]);
      float f_ = sigf(gbuf[DH_ + tid]);
      float g_ = tanhf(gbuf[2 * DH_ + tid]);
      float o_ = sigf(gbuf[3 * DH_ + tid]);
      float c2 = f_ * creg + i_ * g_;
      creg = c2;
      float h2 = o_ * tanhf(c2);
      hall[((size_t)t * B_ + b) * DH_ + tid] = h2;
      hbuf_h[tid] = (_Float16)h2;
    }
    gc0 = gn0; gc1 = gn1;
    __syncthreads();
  }
}

// ---------------------------------------------------------------------------
// out_head: fc_out + tanh + smax + log_softmax (unchanged).
// ---------------------------------------------------------------------------
__global__ __launch_bounds__(256) void out_head(
    const float* __restrict__ hall, const float* __restrict__ fcow,
    const float* __restrict__ fcob, const float* __restrict__ smw,
    const float* __restrict__ smb, float* __restrict__ out) {
  __shared__ __align__(16) float h_lds[16][260];
  __shared__ __align__(16) float fco[16][132];
  __shared__ float lg[16][6];
  const int tid = threadIdx.x;
  const int m0 = blockIdx.x * 16;
  {
    const float* src = hall + (size_t)m0 * DH_;
    for (int e = tid; e < 1024; e += 256) {
      float4 v = reinterpret_cast<const float4*>(src)[e];
      const int r = e >> 6, k = (e & 63) * 4;
      *reinterpret_cast<float4*>(&h_lds[r][k]) = v;
    }
  }
  __syncthreads();
  {
    const int f = tid & 127, half = tid >> 7;
    float acc[8];
    const float fb = fcob[f];
#pragma unroll
    for (int r = 0; r < 8; r++) acc[r] = fb;
    const float* wrow = fcow + (size_t)f * DH_;
    for (int k = 0; k < DH_; k += 4) {
      float4 w4 = *reinterpret_cast<const float4*>(wrow + k);
#pragma unroll
      for (int r = 0; r < 8; r++)
        acc[r] += dot4(w4, *reinterpret_cast<const float4*>(&h_lds[half * 8 + r][k]));
    }
#pragma unroll
    for (int r = 0; r < 8; r++) fco[half * 8 + r][f] = tanhf(acc[r]);
  }
  __syncthreads();
  if (tid < 96) {
    const int r = tid / 6, cc = tid % 6;
    float a = smb[cc];
    const float* sw = smw + cc * 128;
#pragma unroll 4
    for (int k = 0; k < 128; k++) a += sw[k] * fco[r][k];
    lg[r][cc] = a;
  }
  __syncthreads();
  if (tid < 16) {
    const int m = m0 + tid;
    const int t = m >> 8, b = m & 255;
    float mx = lg[tid][0];
#pragma unroll
    for (int cc = 1; cc < 6; cc++) mx = fmaxf(mx, lg[tid][cc]);
    float ssum = 0.f;
#pragma unroll
    for (int cc = 0; cc < 6; cc++) ssum += __expf(lg[tid][cc] - mx);
    float lse = mx + logf(ssum);
#pragma unroll
    for (int cc = 0; cc < 6; cc++)
      out[((size_t)b * T_ + t) * 6 + cc] = lg[tid][cc] - lse;
  }
}

// ---------------------------------------------------------------------------
extern "C" void kernel_launch(void* const* d_in, const int* in_sizes, int n_in,
                              void* d_out, int out_size, void* d_ws, size_t ws_size,
                              hipStream_t stream) {
  const float* mod0  = (const float*)d_in[0];
  const float* mod1  = (const float*)d_in[1];
  const float* mod2  = (const float*)d_in[2];
  const float* umask = (const float*)d_in[3];
  const float* w_ih0 = (const float*)d_in[4];
  const float* w_hh0 = (const float*)d_in[5];
  const float* b_ih0 = (const float*)d_in[6];
  const float* b_hh0 = (const float*)d_in[7];
  const float* fc_w0 = (const float*)d_in[8];
  const float* fc_b0 = (const float*)d_in[9];
  const float* w_ih1 = (const float*)d_in[10];
  const float* w_hh1 = (const float*)d_in[11];
  const float* b_ih1 = (const float*)d_in[12];
  const float* b_hh1 = (const float*)d_in[13];
  const float* fc_w1 = (const float*)d_in[14];
  const float* fc_b1 = (const float*)d_in[15];
  const float* w_ih2 = (const float*)d_in[16];
  const float* w_hh2 = (const float*)d_in[17];
  const float* b_ih2 = (const float*)d_in[18];
  const float* b_hh2 = (const float*)d_in[19];
  const float* fc_w2 = (const float*)d_in[20];
  const float* fc_b2 = (const float*)d_in[21];
  const float* w_ih_d = (const float*)d_in[22];
  const float* w_hh_d = (const float*)d_in[23];
  const float* b_ih_d = (const float*)d_in[24];
  const float* b_hh_d = (const float*)d_in[25];
  const float* fco_w  = (const float*)d_in[26];
  const float* fco_b  = (const float*)d_in[27];
  const float* sm_w   = (const float*)d_in[28];
  const float* sm_b   = (const float*)d_in[29];

  // workspace layout (float units):
  //   [0, M*1280): gx0|gx1|gx2 -> reused as gxd [0,M*1024) + hall [M*1024,M*1280)
  float* ws    = (float*)d_ws;
  float* gx0   = ws;                                  // M*512
  float* gx1   = gx0 + (size_t)M_ * 512;              // M*256
  float* gx2   = gx1 + (size_t)M_ * 256;              // M*512
  float* gxd   = ws;                                  // M*1024 (reuse)
  float* hall  = ws + (size_t)M_ * 1024;              // M*256
  unsigned short* dfeat_h = (unsigned short*)(ws + (size_t)M_ * 1280);  // M*256 bf16
  float* tail  = ws + (size_t)M_ * 1408;
  float* biasd = tail;                                // 1024
  float* bias0 = biasd + 1024;                        // 512
  float* bias1 = bias0 + 512;                         // 256
  float* bias2 = bias1 + 256;                         // 512
  unsigned int* wpk   = (unsigned int*)(bias2 + 512); // 1024*96
  unsigned int* wldsg = wpk + 1024 * 96;              // 32768
  unsigned int* wpk0  = wldsg + 32768;                // 512*64
  unsigned int* wpk1  = wpk0 + 512 * 64;              // 256*32
  unsigned int* wpk2  = wpk1 + 256 * 32;              // 512*64
  unsigned int* fcT0  = wpk2 + 512 * 64;              // 6400
  unsigned int* fcT1  = fcT0 + 6400;                  // 1600
  unsigned int* fcT2  = fcT1 + 1600;                  // 6400
  unsigned short* w0b = (unsigned short*)(fcT2 + 6400);   // 512*320
  unsigned short* w1b = w0b + 512 * 320;                  // 256*128
  unsigned short* w2b = w1b + 256 * 128;                  // 512*512
  unsigned short* wdb = w2b + 512 * 512;                  // 1024*256

  prep_kernel<<<256, 256, 0, stream>>>(w_ih_d, w_hh_d, b_ih_d, b_hh_d,
      b_ih0, b_hh0, b_ih1, b_hh1, b_ih2, b_hh2,
      w_hh0, w_hh1, w_hh2, w_ih0, w_ih1, w_ih2, fc_w0, fc_w1, fc_w2,
      dfeat_h, biasd, bias0, bias1, bias2, wpk, wldsg,
      wpk0, wpk1, wpk2, fcT0, fcT1, fcT2, w0b, w1b, w2b, wdb);

  // input projections (bf16 MFMA)
  mfma_gemm<false><<<8 * 512, 256, 0, stream>>>(mod0, w0b, bias0, umask, gx0, 300, 320, 512);
  mfma_gemm<false><<<4 * 512, 256, 0, stream>>>(mod1, w1b, bias1, umask, gx1, 100, 128, 256);
  mfma_gemm<false><<<8 * 512, 256, 0, stream>>>(mod2, w2b, bias2, umask, gx2, 512, 512, 512);

  // modality scans
  mod_recur<128, 100><<<512, 512, 0, stream>>>(
      gx0, gx2, wpk0, wpk2, fcT0, fcT2, fc_b0, fc_b2, 0, 150, umask, dfeat_h);
  mod_recur<64, 50><<<256, 256, 0, stream>>>(
      gx1, gx1, wpk1, wpk1, fcT1, fcT1, fc_b1, fc_b1, 100, 100, umask, dfeat_h);

  // dialogue input projection (bf16 MFMA, X already bf16)
  mfma_gemm<true><<<16 * 512, 256, 0, stream>>>(dfeat_h, wdb, biasd, nullptr, gxd, 256, 256, 1024);

  hipFuncSetAttribute(reinterpret_cast<const void*>(dlg_recur),
                      hipFuncAttributeMaxDynamicSharedMemorySize, DLG_LDS_BYTES);
  dlg_recur<<<256, 512, DLG_LDS_BYTES, stream>>>(gxd, wpk, wldsg, hall);

  out_head<<<M_ / 16, 256, 0, stream>>>(hall, fco_w, fco_b, sm_w, sm_b, (float*)d_out);
}

// Round 7
// 893.327 us; speedup vs baseline: 9.7964x; 1.1533x over previous
//
#include <hip/hip_runtime.h>

#define B_ 256
#define T_ 128
#define M_ (B_ * T_)
#define DH_ 256

__device__ __forceinline__ float sigf(float x) { return 1.0f / (1.0f + __expf(-x)); }
__device__ __forceinline__ float dot4(float4 a, float4 b) {
  return a.x * b.x + a.y * b.y + a.z * b.z + a.w * b.w;
}

typedef _Float16 half2v __attribute__((ext_vector_type(2)));
typedef short short8 __attribute__((ext_vector_type(8)));
typedef float f32x4 __attribute__((ext_vector_type(4)));

__device__ __forceinline__ float fdot2f(unsigned int w, unsigned int h, float acc) {
  half2v wv = __builtin_bit_cast(half2v, w);
  half2v hv = __builtin_bit_cast(half2v, h);
#if __has_builtin(__builtin_amdgcn_fdot2)
  return __builtin_amdgcn_fdot2(wv, hv, acc, false);
#else
  return acc + (float)wv[0] * (float)hv[0] + (float)wv[1] * (float)hv[1];
#endif
}
__device__ __forceinline__ unsigned int pk16(float a, float b) {
  unsigned short lo = __builtin_bit_cast(unsigned short, (_Float16)a);
  unsigned short hi = __builtin_bit_cast(unsigned short, (_Float16)b);
  return (unsigned int)lo | ((unsigned int)hi << 16);
}
__device__ __forceinline__ unsigned short bf16c(float x) {  // RNE f32->bf16
  unsigned int u = __builtin_bit_cast(unsigned int, x);
  return (unsigned short)((u + 0x7FFFu + ((u >> 16) & 1u)) >> 16);
}
__device__ __forceinline__ unsigned int bfpk(float a, float b) {
  return (unsigned int)bf16c(a) | ((unsigned int)bf16c(b) << 16);
}

// ---------------------------------------------------------------------------
// prep: combined biases; bf16 zero-padded GEMM weights; fp16-packed recurrent
// weights. Layouts:
//   wpkX  [4H rows][H/2 u32]          modality gate rows (register-resident)
//   fcTX  [H/16 j4][F][4 u32]         FC weights, b128-readable per f
//   wpk   [1024][96 u32]              dialogue reg part (pairs 0..95)
//   wldsg [8 jj][1024 r][4 u32]       dialogue LDS part (pairs 96..127), b128
// ---------------------------------------------------------------------------
__global__ void prep_kernel(const float* __restrict__ w_ih_d, const float* __restrict__ w_hh_d,
                            const float* __restrict__ b_ih_d, const float* __restrict__ b_hh_d,
                            const float* __restrict__ b_ih0, const float* __restrict__ b_hh0,
                            const float* __restrict__ b_ih1, const float* __restrict__ b_hh1,
                            const float* __restrict__ b_ih2, const float* __restrict__ b_hh2,
                            const float* __restrict__ w_hh0, const float* __restrict__ w_hh1,
                            const float* __restrict__ w_hh2,
                            const float* __restrict__ w_ih0, const float* __restrict__ w_ih1,
                            const float* __restrict__ w_ih2,
                            const float* __restrict__ fc_w0, const float* __restrict__ fc_w1,
                            const float* __restrict__ fc_w2,
                            unsigned short* __restrict__ dfeat_h,
                            float* __restrict__ biasd, float* __restrict__ bias0,
                            float* __restrict__ bias1, float* __restrict__ bias2,
                            unsigned int* __restrict__ wpk, unsigned int* __restrict__ wldsg,
                            unsigned int* __restrict__ wpk0, unsigned int* __restrict__ wpk1,
                            unsigned int* __restrict__ wpk2,
                            unsigned int* __restrict__ fcT0, unsigned int* __restrict__ fcT1,
                            unsigned int* __restrict__ fcT2,
                            unsigned short* __restrict__ w0b, unsigned short* __restrict__ w1b,
                            unsigned short* __restrict__ w2b, unsigned short* __restrict__ wdb) {
  int idx = blockIdx.x * blockDim.x + threadIdx.x;
  int stride = gridDim.x * blockDim.x;
  // bf16 GEMM weights (K zero-padded to multiple of 32)
  for (int i = idx; i < 512 * 320; i += stride) {
    int r = i / 320, k = i % 320;
    w0b[i] = (k < 300) ? bf16c(w_ih0[(size_t)r * 300 + k]) : (unsigned short)0;
  }
  for (int i = idx; i < 256 * 128; i += stride) {
    int r = i >> 7, k = i & 127;
    w1b[i] = (k < 100) ? bf16c(w_ih1[(size_t)r * 100 + k]) : (unsigned short)0;
  }
  for (int i = idx; i < 512 * 512; i += stride) w2b[i] = bf16c(w_ih2[i]);
  for (int i = idx; i < 1024 * 256; i += stride) {
    int r = i >> 8, k = i & 255;
    wdb[i] = (k < 250) ? bf16c(w_ih_d[(size_t)r * 250 + k]) : (unsigned short)0;
  }
  for (int i = idx; i < M_ * 6; i += stride)   // zero dfeat_h pad cols 250..255
    dfeat_h[(size_t)(i / 6) * 256 + 250 + (i % 6)] = 0;
  // dialogue recurrent weights fp16: reg part (pairs 0..95)
  for (int i = idx; i < 1024 * 96; i += stride) {
    int r = i / 96, k0 = (i % 96) * 2;
    wpk[i] = pk16(w_hh_d[(size_t)r * 256 + k0], w_hh_d[(size_t)r * 256 + k0 + 1]);
  }
  // dialogue LDS part, b128 layout: i = (jj*1024 + r)*4 + q, pair p = 96+4*jj+q
  for (int i = idx; i < 32768; i += stride) {
    int jj = i >> 12, rem = i & 4095, r = rem >> 2, q = rem & 3;
    int p = 96 + 4 * jj + q;
    wldsg[i] = pk16(w_hh_d[(size_t)r * 256 + 2 * p], w_hh_d[(size_t)r * 256 + 2 * p + 1]);
  }
  // modality recurrent weights (row-major packed pairs)
  for (int i = idx; i < 512 * 64; i += stride) {
    int r = i >> 6, p = (i & 63) * 2;
    wpk0[i] = pk16(w_hh0[(size_t)r * 128 + p], w_hh0[(size_t)r * 128 + p + 1]);
    wpk2[i] = pk16(w_hh2[(size_t)r * 128 + p], w_hh2[(size_t)r * 128 + p + 1]);
  }
  for (int i = idx; i < 256 * 32; i += stride) {
    int r = i >> 5, p = (i & 31) * 2;
    wpk1[i] = pk16(w_hh1[(size_t)r * 64 + p], w_hh1[(size_t)r * 64 + p + 1]);
  }
  // FC weights: fcT[(j4*F + f)*4 + q] = pack(fc_w[f][8*j4+2q], fc_w[f][8*j4+2q+1])
  for (int i = idx; i < 16 * 100 * 4; i += stride) {
    int j4 = i / 400, rem = i % 400, f = rem >> 2, q = rem & 3;
    int k = 8 * j4 + 2 * q;
    fcT0[i] = pk16(fc_w0[(size_t)f * 128 + k], fc_w0[(size_t)f * 128 + k + 1]);
    fcT2[i] = pk16(fc_w2[(size_t)f * 128 + k], fc_w2[(size_t)f * 128 + k + 1]);
  }
  for (int i = idx; i < 8 * 50 * 4; i += stride) {
    int j4 = i / 200, rem = i % 200, f = rem >> 2, q = rem & 3;
    int k = 8 * j4 + 2 * q;
    fcT1[i] = pk16(fc_w1[(size_t)f * 64 + k], fc_w1[(size_t)f * 64 + k + 1]);
  }
  for (int i = idx; i < 1024; i += stride) biasd[i] = b_ih_d[i] + b_hh_d[i];
  for (int i = idx; i < 512; i += stride) bias0[i] = b_ih0[i] + b_hh0[i];
  for (int i = idx; i < 256; i += stride) bias1[i] = b_ih1[i] + b_hh1[i];
  for (int i = idx; i < 512; i += stride) bias2[i] = b_ih2[i] + b_hh2[i];
}

// ---------------------------------------------------------------------------
// mfma_gemm: C[m][n] = scale * sum_k X[m][k]*W[n][k] + bias[n], bf16 MFMA.
// (unchanged from round 6 — verified)
// ---------------------------------------------------------------------------
template <bool XF16>
__global__ __launch_bounds__(256) void mfma_gemm(
    const void* __restrict__ Xv, const unsigned short* __restrict__ Wb,
    const float* __restrict__ bias, const float* __restrict__ umask,
    float* __restrict__ C, int K, int Kp, int N) {
  __shared__ __align__(16) unsigned short Xs[64][40];
  __shared__ __align__(16) unsigned short Ws[64][40];
  const int tid = threadIdx.x;
  const int d = blockIdx.x;
  const int nx = N >> 6;
  const int n0 = ((d % (nx << 3)) >> 3) << 6;
  const int m0 = (((d / (nx << 3)) << 3) + (d & 7)) << 6;
  const int srow = tid >> 2, kq = tid & 3;
  const int w = tid >> 6, lane = tid & 63;
  const int lr = lane & 15, lk = lane >> 4;
  const float* Xf = nullptr;
  const unsigned short* Xh = nullptr;
  if constexpr (XF16) {
    Xh = (const unsigned short*)Xv + (size_t)(m0 + srow) * Kp;
  } else {
    const int t = m0 >> 8, b0 = m0 & 255;
    Xf = (const float*)Xv + ((size_t)(b0 + srow) * T_ + t) * K;
  }
  const unsigned short* Wr = Wb + (size_t)(n0 + srow) * Kp;
  f32x4 acc[4];
#pragma unroll
  for (int j = 0; j < 4; j++) acc[j] = (f32x4){0.f, 0.f, 0.f, 0.f};

  for (int k0 = 0; k0 < Kp; k0 += 32) {
    uint4 xa;
    const int kk = k0 + kq * 8;
    if constexpr (XF16) {
      xa = *reinterpret_cast<const uint4*>(Xh + kk);
    } else {
      float4 va = (kk + 3 < K) ? *reinterpret_cast<const float4*>(Xf + kk)
                               : make_float4(0.f, 0.f, 0.f, 0.f);
      float4 vb = (kk + 7 < K) ? *reinterpret_cast<const float4*>(Xf + kk + 4)
                               : make_float4(0.f, 0.f, 0.f, 0.f);
      xa.x = bfpk(va.x, va.y); xa.y = bfpk(va.z, va.w);
      xa.z = bfpk(vb.x, vb.y); xa.w = bfpk(vb.z, vb.w);
    }
    uint4 wv = *reinterpret_cast<const uint4*>(Wr + kk);
    __syncthreads();
    *reinterpret_cast<uint4*>(&Xs[srow][kq * 8]) = xa;
    *reinterpret_cast<uint4*>(&Ws[srow][kq * 8]) = wv;
    __syncthreads();
    short8 af = *reinterpret_cast<const short8*>(&Xs[w * 16 + lr][lk * 8]);
#pragma unroll
    for (int j = 0; j < 4; j++) {
      short8 bf = *reinterpret_cast<const short8*>(&Ws[j * 16 + lr][lk * 8]);
      acc[j] = __builtin_amdgcn_mfma_f32_16x16x32_bf16(af, bf, acc[j], 0, 0, 0);
    }
  }
#pragma unroll
  for (int j = 0; j < 4; j++) {
    const int col = n0 + j * 16 + lr;
    const float bv = bias[col];
#pragma unroll
    for (int r = 0; r < 4; r++) {
      const int mrow = m0 + w * 16 + lk * 4 + r;
      float um = 1.0f;
      if constexpr (!XF16)
        um = umask[((m0 & 255) + w * 16 + lk * 4 + r) * T_ + (m0 >> 8)];
      C[(size_t)mrow * N + col] = acc[j][r] * um + bv;
    }
  }
}

// ---------------------------------------------------------------------------
// mod_scan: fused modality LSTM scans. 768 blocks x 256 threads.
//   blocks [0,256)   : mod0, H=128 (G=2 gate rows/thread)
//   blocks [256,512) : mod2, H=128
//   blocks [512,768) : mod1, H=64  (G=1)
// __launch_bounds__(256,2) -> 256-VGPR cap so gate weights (128 VGPR for
// H=128) genuinely stay register-resident (round-6 lesson: (NT,4)'s 128-cap
// silently demoted them to per-step L2 re-reads, 26 TB/s).
// FC is software-pipelined: FC(h_{t-1}) computed by waves 2-3 during step t's
// gate phase, reusing the gate phase's h registers; cell on waves 0-1.
// ---------------------------------------------------------------------------
struct ModScanArgs {
  const float* gx0; const float* gx1; const float* gx2;
  const unsigned int* wk0; const unsigned int* wk1; const unsigned int* wk2;
  const unsigned int* ft0; const unsigned int* ft1; const unsigned int* ft2;
  const float* fb0; const float* fb1; const float* fb2;
};

__device__ __forceinline__ void mod_body128(
    const float* __restrict__ gx, const unsigned int* __restrict__ wk,
    const unsigned int* __restrict__ ft, const float* __restrict__ fcb,
    int col, int b, const float* __restrict__ umask,
    unsigned short* __restrict__ dfeat_h, unsigned int* smem) {
  unsigned int* fcT = smem;                 // 6400 u32
  float* gbuf = (float*)(smem + 6400);      // 512 f32
  unsigned int* hbuf = smem + 6912;         // 64 u32
  const int tid = threadIdx.x;
  const bool isfc = (tid >= 128 && tid < 228);
  const int f = tid - 128;
  for (int i = tid; i < 6400; i += 256) fcT[i] = ft[i];
  uint4 wrA[16], wrB[16];
  {
    const uint4* wpA = reinterpret_cast<const uint4*>(wk + (size_t)tid * 64);
    const uint4* wpB = reinterpret_cast<const uint4*>(wk + (size_t)(tid + 256) * 64);
#pragma unroll
    for (int j = 0; j < 16; j++) { wrA[j] = wpA[j]; wrB[j] = wpB[j]; }
  }
  if (tid < 64) hbuf[tid] = 0u;
  float creg = 0.f;
  __syncthreads();
  const uint4* h4 = reinterpret_cast<const uint4*>(hbuf);
  const uint4* fcT4 = reinterpret_cast<const uint4*>(fcT);
  const float* gp = gx + (size_t)b * 512 + tid;
  const float* ump = umask + b * T_;
  const float fb = isfc ? fcb[f] : 0.f;
  float gcA = gp[0], gcB = gp[256];
  for (int t = 0; t < T_; t++) {
    float gnA = 0.f, gnB = 0.f;
    if (t + 1 < T_) {
      gnA = gp[(size_t)(t + 1) * B_ * 512];
      gnB = gp[(size_t)(t + 1) * B_ * 512 + 256];
    }
    float a0 = 0.f, a1 = 0.f, a2 = 0.f, a3 = 0.f;
    float d0 = 0.f, d1 = 0.f, d2 = 0.f, d3 = 0.f;
    float fa = fb;
#pragma unroll
    for (int j = 0; j < 16; j++) {
      uint4 hv = h4[j];
      a0 = fdot2f(wrA[j].x, hv.x, a0);
      a1 = fdot2f(wrA[j].y, hv.y, a1);
      a2 = fdot2f(wrA[j].z, hv.z, a2);
      a3 = fdot2f(wrA[j].w, hv.w, a3);
      d0 = fdot2f(wrB[j].x, hv.x, d0);
      d1 = fdot2f(wrB[j].y, hv.y, d1);
      d2 = fdot2f(wrB[j].z, hv.z, d2);
      d3 = fdot2f(wrB[j].w, hv.w, d3);
      if (isfc) {
        uint4 fv = fcT4[j * 100 + f];
        fa = fdot2f(fv.x, hv.x, fa);
        fa = fdot2f(fv.y, hv.y, fa);
        fa = fdot2f(fv.z, hv.z, fa);
        fa = fdot2f(fv.w, hv.w, fa);
      }
    }
    if (isfc && t > 0)   // FC(h_{t-1}) = output row t-1
      dfeat_h[((size_t)(t - 1) * B_ + b) * 256 + col + f] = bf16c(tanhf(fa) * ump[t - 1]);
    gbuf[tid] = (a0 + a1) + (a2 + a3) + gcA;
    gbuf[tid + 256] = (d0 + d1) + (d2 + d3) + gcB;
    gcA = gnA; gcB = gnB;
    __syncthreads();                        // S1: gates ready, h reads done
    if (tid < 128) {
      float i_ = sigf(gbuf[tid]);
      float f_ = sigf(gbuf[128 + tid]);
      float g_ = tanhf(gbuf[256 + tid]);
      float o_ = sigf(gbuf[384 + tid]);
      float cc = f_ * creg + i_ * g_;
      creg = cc;
      float h2 = tanhf(o_ * tanhf(cc));     // extra tanh on hidden state
      float hp = __shfl_xor(h2, 1);
      if ((tid & 1) == 0) hbuf[tid >> 1] = pk16(h2, hp);
    }
    __syncthreads();                        // S2: h_t staged
  }
  if (isfc) {                               // epilogue FC for t = T-1
    float fa = fb;
#pragma unroll
    for (int j = 0; j < 16; j++) {
      uint4 hv = h4[j];
      uint4 fv = fcT4[j * 100 + f];
      fa = fdot2f(fv.x, hv.x, fa);
      fa = fdot2f(fv.y, hv.y, fa);
      fa = fdot2f(fv.z, hv.z, fa);
      fa = fdot2f(fv.w, hv.w, fa);
    }
    dfeat_h[((size_t)(T_ - 1) * B_ + b) * 256 + col + f] = bf16c(tanhf(fa) * ump[T_ - 1]);
  }
}

__device__ __forceinline__ void mod_body64(
    const float* __restrict__ gx, const unsigned int* __restrict__ wk,
    const unsigned int* __restrict__ ft, const float* __restrict__ fcb,
    int col, int b, const float* __restrict__ umask,
    unsigned short* __restrict__ dfeat_h, unsigned int* smem) {
  unsigned int* fcT = smem;                 // 1600 u32
  float* gbuf = (float*)(smem + 6400);      // 256 f32
  unsigned int* hbuf = smem + 6912;         // 32 u32
  const int tid = threadIdx.x;
  const bool isfc = (tid >= 64 && tid < 114);
  const int f = tid - 64;
  for (int i = tid; i < 1600; i += 256) fcT[i] = ft[i];
  uint4 wr[8];
  {
    const uint4* wp = reinterpret_cast<const uint4*>(wk + (size_t)tid * 32);
#pragma unroll
    for (int j = 0; j < 8; j++) wr[j] = wp[j];
  }
  if (tid < 32) hbuf[tid] = 0u;
  float creg = 0.f;
  __syncthreads();
  const uint4* h4 = reinterpret_cast<const uint4*>(hbuf);
  const uint4* fcT4 = reinterpret_cast<const uint4*>(fcT);
  const float* gp = gx + (size_t)b * 256 + tid;
  const float* ump = umask + b * T_;
  const float fb = isfc ? fcb[f] : 0.f;
  float gc = gp[0];
  for (int t = 0; t < T_; t++) {
    float gn = (t + 1 < T_) ? gp[(size_t)(t + 1) * B_ * 256] : 0.f;
    float a0 = 0.f, a1 = 0.f, a2 = 0.f, a3 = 0.f;
    float fa = fb;
#pragma unroll
    for (int j = 0; j < 8; j++) {
      uint4 hv = h4[j];
      a0 = fdot2f(wr[j].x, hv.x, a0);
      a1 = fdot2f(wr[j].y, hv.y, a1);
      a2 = fdot2f(wr[j].z, hv.z, a2);
      a3 = fdot2f(wr[j].w, hv.w, a3);
      if (isfc) {
        uint4 fv = fcT4[j * 50 + f];
        fa = fdot2f(fv.x, hv.x, fa);
        fa = fdot2f(fv.y, hv.y, fa);
        fa = fdot2f(fv.z, hv.z, fa);
        fa = fdot2f(fv.w, hv.w, fa);
      }
    }
    if (isfc && t > 0)
      dfeat_h[((size_t)(t - 1) * B_ + b) * 256 + col + f] = bf16c(tanhf(fa) * ump[t - 1]);
    gbuf[tid] = (a0 + a1) + (a2 + a3) + gc;
    gc = gn;
    __syncthreads();                        // S1
    if (tid < 64) {
      float i_ = sigf(gbuf[tid]);
      float f_ = sigf(gbuf[64 + tid]);
      float g_ = tanhf(gbuf[128 + tid]);
      float o_ = sigf(gbuf[192 + tid]);
      float cc = f_ * creg + i_ * g_;
      creg = cc;
      float h2 = tanhf(o_ * tanhf(cc));
      float hp = __shfl_xor(h2, 1);
      if ((tid & 1) == 0) hbuf[tid >> 1] = pk16(h2, hp);
    }
    __syncthreads();                        // S2
  }
  if (isfc) {
    float fa = fb;
#pragma unroll
    for (int j = 0; j < 8; j++) {
      uint4 hv = h4[j];
      uint4 fv = fcT4[j * 50 + f];
      fa = fdot2f(fv.x, hv.x, fa);
      fa = fdot2f(fv.y, hv.y, fa);
      fa = fdot2f(fv.z, hv.z, fa);
      fa = fdot2f(fv.w, hv.w, fa);
    }
    dfeat_h[((size_t)(T_ - 1) * B_ + b) * 256 + col + f] = bf16c(tanhf(fa) * ump[T_ - 1]);
  }
}

__global__ __launch_bounds__(256, 2) void mod_scan(ModScanArgs a,
    const float* __restrict__ umask, unsigned short* __restrict__ dfeat_h) {
  __shared__ __align__(16) unsigned int smem[6976];   // fcT | gbuf | hbuf
  const int blk = blockIdx.x;
  if (blk < 512) {
    const int mi = blk >> 8, b = blk & 255;
    mod_body128(mi ? a.gx2 : a.gx0, mi ? a.wk2 : a.wk0, mi ? a.ft2 : a.ft0,
                mi ? a.fb2 : a.fb0, mi ? 150 : 0, b, umask, dfeat_h, smem);
  } else {
    mod_body64(a.gx1, a.wk1, a.ft1, a.fb1, 100, blk - 512, umask, dfeat_h, smem);
  }
}

// ---------------------------------------------------------------------------
// dlg_recur: as round 6, but LDS weight part now b128 layout
// (16 ds_read_b128 instead of 32 ds_read_b64 per thread per step).
// ---------------------------------------------------------------------------
#define DLG_LDS_BYTES (131072 + 4096 + 512)

__global__ __launch_bounds__(512, 2) void dlg_recur(
    const float* __restrict__ gxd, const unsigned int* __restrict__ wpk,
    const unsigned int* __restrict__ wldsg, float* __restrict__ hall) {
  extern __shared__ char smem[];
  unsigned int* wl = (unsigned int*)smem;                       // [8][1024][4]
  float* gbuf = (float*)(smem + 131072);                        // [1024]
  _Float16* hbuf_h = (_Float16*)(smem + 131072 + 4096);         // [256]
  const uint4* hbuf4 = (const uint4*)hbuf_h;                    // [32]
  const uint4* wl4 = (const uint4*)wl;
  const int tid = threadIdx.x;
  const int b = blockIdx.x;

  for (int i = tid; i < 32768; i += 512) wl[i] = wldsg[i];
  unsigned int wr0[96], wr1[96];
  {
    const uint4* p0 = reinterpret_cast<const uint4*>(wpk + (size_t)tid * 96);
    const uint4* p1 = reinterpret_cast<const uint4*>(wpk + (size_t)(tid + 512) * 96);
#pragma unroll
    for (int j = 0; j < 24; j++) {
      uint4 v0 = p0[j], v1 = p1[j];
      wr0[4 * j + 0] = v0.x; wr0[4 * j + 1] = v0.y; wr0[4 * j + 2] = v0.z; wr0[4 * j + 3] = v0.w;
      wr1[4 * j + 0] = v1.x; wr1[4 * j + 1] = v1.y; wr1[4 * j + 2] = v1.z; wr1[4 * j + 3] = v1.w;
    }
  }
  if (tid < 32) reinterpret_cast<uint4*>(const_cast<_Float16*>(hbuf_h))[tid] = uint4{0, 0, 0, 0};
  float creg = 0.f;
  __syncthreads();

  const float* gbase = gxd + (size_t)b * 1024 + tid;
  float gc0 = gbase[0], gc1 = gbase[512];
  for (int t = 0; t < T_; t++) {
    float gn0 = 0.f, gn1 = 0.f;
    if (t + 1 < T_) {
      gn0 = gbase[(size_t)(t + 1) * B_ * 1024];
      gn1 = gbase[(size_t)(t + 1) * B_ * 1024 + 512];
    }
    float a0 = 0.f, a1 = 0.f;
#pragma unroll
    for (int j = 0; j < 24; j++) {          // pairs 0..95 (registers)
      uint4 hv = hbuf4[j];
      a0 = fdot2f(wr0[4 * j + 0], hv.x, a0); a1 = fdot2f(wr1[4 * j + 0], hv.x, a1);
      a0 = fdot2f(wr0[4 * j + 1], hv.y, a0); a1 = fdot2f(wr1[4 * j + 1], hv.y, a1);
      a0 = fdot2f(wr0[4 * j + 2], hv.z, a0); a1 = fdot2f(wr1[4 * j + 2], hv.z, a1);
      a0 = fdot2f(wr0[4 * j + 3], hv.w, a0); a1 = fdot2f(wr1[4 * j + 3], hv.w, a1);
    }
#pragma unroll
    for (int jj = 0; jj < 8; jj++) {        // pairs 96..127 (LDS, b128)
      uint4 hv = hbuf4[24 + jj];
      uint4 wa = wl4[jj * 1024 + tid];
      uint4 wc = wl4[jj * 1024 + tid + 512];
      a0 = fdot2f(wa.x, hv.x, a0); a1 = fdot2f(wc.x, hv.x, a1);
      a0 = fdot2f(wa.y, hv.y, a0); a1 = fdot2f(wc.y, hv.y, a1);
      a0 = fdot2f(wa.z, hv.z, a0); a1 = fdot2f(wc.z, hv.z, a1);
      a0 = fdot2f(wa.w, hv.w, a0); a1 = fdot2f(wc.w, hv.w, a1);
    }
    gbuf[tid] = a0 + gc0;
    gbuf[tid + 512] = a1 + gc1;
    __syncthreads();
    if (tid < DH_) {
      float i_ = sigf(gbuf[tid]);
      float f_ = sigf(gbuf[DH_ + tid]);
      float g_ = tanhf(gbuf[2 * DH_ + tid]);
      float o_ = sigf(gbuf[3 * DH_ + tid]);
      float c2 = f_ * creg + i_ * g_;
      creg = c2;
      float h2 = o_ * tanhf(c2);
      hall[((size_t)t * B_ + b) * DH_ + tid] = h2;
      hbuf_h[tid] = (_Float16)h2;
    }
    gc0 = gn0; gc1 = gn1;
    __syncthreads();
  }
}

// ---------------------------------------------------------------------------
// out_head: fc_out + tanh + smax + log_softmax (unchanged).
// ---------------------------------------------------------------------------
__global__ __launch_bounds__(256) void out_head(
    const float* __restrict__ hall, const float* __restrict__ fcow,
    const float* __restrict__ fcob, const float* __restrict__ smw,
    const float* __restrict__ smb, float* __restrict__ out) {
  __shared__ __align__(16) float h_lds[16][260];
  __shared__ __align__(16) float fco[16][132];
  __shared__ float lg[16][6];
  const int tid = threadIdx.x;
  const int m0 = blockIdx.x * 16;
  {
    const float* src = hall + (size_t)m0 * DH_;
    for (int e = tid; e < 1024; e += 256) {
      float4 v = reinterpret_cast<const float4*>(src)[e];
      const int r = e >> 6, k = (e & 63) * 4;
      *reinterpret_cast<float4*>(&h_lds[r][k]) = v;
    }
  }
  __syncthreads();
  {
    const int f = tid & 127, half = tid >> 7;
    float acc[8];
    const float fb = fcob[f];
#pragma unroll
    for (int r = 0; r < 8; r++) acc[r] = fb;
    const float* wrow = fcow + (size_t)f * DH_;
    for (int k = 0; k < DH_; k += 4) {
      float4 w4 = *reinterpret_cast<const float4*>(wrow + k);
#pragma unroll
      for (int r = 0; r < 8; r++)
        acc[r] += dot4(w4, *reinterpret_cast<const float4*>(&h_lds[half * 8 + r][k]));
    }
#pragma unroll
    for (int r = 0; r < 8; r++) fco[half * 8 + r][f] = tanhf(acc[r]);
  }
  __syncthreads();
  if (tid < 96) {
    const int r = tid / 6, cc = tid % 6;
    float a = smb[cc];
    const float* sw = smw + cc * 128;
#pragma unroll 4
    for (int k = 0; k < 128; k++) a += sw[k] * fco[r][k];
    lg[r][cc] = a;
  }
  __syncthreads();
  if (tid < 16) {
    const int m = m0 + tid;
    const int t = m >> 8, b = m & 255;
    float mx = lg[tid][0];
#pragma unroll
    for (int cc = 1; cc < 6; cc++) mx = fmaxf(mx, lg[tid][cc]);
    float ssum = 0.f;
#pragma unroll
    for (int cc = 0; cc < 6; cc++) ssum += __expf(lg[tid][cc] - mx);
    float lse = mx + logf(ssum);
#pragma unroll
    for (int cc = 0; cc < 6; cc++)
      out[((size_t)b * T_ + t) * 6 + cc] = lg[tid][cc] - lse;
  }
}

// ---------------------------------------------------------------------------
extern "C" void kernel_launch(void* const* d_in, const int* in_sizes, int n_in,
                              void* d_out, int out_size, void* d_ws, size_t ws_size,
                              hipStream_t stream) {
  const float* mod0  = (const float*)d_in[0];
  const float* mod1  = (const float*)d_in[1];
  const float* mod2  = (const float*)d_in[2];
  const float* umask = (const float*)d_in[3];
  const float* w_ih0 = (const float*)d_in[4];
  const float* w_hh0 = (const float*)d_in[5];
  const float* b_ih0 = (const float*)d_in[6];
  const float* b_hh0 = (const float*)d_in[7];
  const float* fc_w0 = (const float*)d_in[8];
  const float* fc_b0 = (const float*)d_in[9];
  const float* w_ih1 = (const float*)d_in[10];
  const float* w_hh1 = (const float*)d_in[11];
  const float* b_ih1 = (const float*)d_in[12];
  const float* b_hh1 = (const float*)d_in[13];
  const float* fc_w1 = (const float*)d_in[14];
  const float* fc_b1 = (const float*)d_in[15];
  const float* w_ih2 = (const float*)d_in[16];
  const float* w_hh2 = (const float*)d_in[17];
  const float* b_ih2 = (const float*)d_in[18];
  const float* b_hh2 = (const float*)d_in[19];
  const float* fc_w2 = (const float*)d_in[20];
  const float* fc_b2 = (const float*)d_in[21];
  const float* w_ih_d = (const float*)d_in[22];
  const float* w_hh_d = (const float*)d_in[23];
  const float* b_ih_d = (const float*)d_in[24];
  const float* b_hh_d = (const float*)d_in[25];
  const float* fco_w  = (const float*)d_in[26];
  const float* fco_b  = (const float*)d_in[27];
  const float* sm_w   = (const float*)d_in[28];
  const float* sm_b   = (const float*)d_in[29];

  // workspace layout (float units):
  //   [0, M*1280): gx0|gx1|gx2 -> reused as gxd [0,M*1024) + hall [M*1024,M*1280)
  float* ws    = (float*)d_ws;
  float* gx0   = ws;                                  // M*512
  float* gx1   = gx0 + (size_t)M_ * 512;              // M*256
  float* gx2   = gx1 + (size_t)M_ * 256;              // M*512
  float* gxd   = ws;                                  // M*1024 (reuse)
  float* hall  = ws + (size_t)M_ * 1024;              // M*256
  unsigned short* dfeat_h = (unsigned short*)(ws + (size_t)M_ * 1280);  // M*256 bf16
  float* tail  = ws + (size_t)M_ * 1408;
  float* biasd = tail;                                // 1024
  float* bias0 = biasd + 1024;                        // 512
  float* bias1 = bias0 + 512;                         // 256
  float* bias2 = bias1 + 256;                         // 512
  unsigned int* wpk   = (unsigned int*)(bias2 + 512); // 1024*96
  unsigned int* wldsg = wpk + 1024 * 96;              // 32768
  unsigned int* wpk0  = wldsg + 32768;                // 512*64
  unsigned int* wpk1  = wpk0 + 512 * 64;              // 256*32
  unsigned int* wpk2  = wpk1 + 256 * 32;              // 512*64
  unsigned int* fcT0  = wpk2 + 512 * 64;              // 6400
  unsigned int* fcT1  = fcT0 + 6400;                  // 1600
  unsigned int* fcT2  = fcT1 + 1600;                  // 6400
  unsigned short* w0b = (unsigned short*)(fcT2 + 6400);   // 512*320
  unsigned short* w1b = w0b + 512 * 320;                  // 256*128
  unsigned short* w2b = w1b + 256 * 128;                  // 512*512
  unsigned short* wdb = w2b + 512 * 512;                  // 1024*256

  prep_kernel<<<256, 256, 0, stream>>>(w_ih_d, w_hh_d, b_ih_d, b_hh_d,
      b_ih0, b_hh0, b_ih1, b_hh1, b_ih2, b_hh2,
      w_hh0, w_hh1, w_hh2, w_ih0, w_ih1, w_ih2, fc_w0, fc_w1, fc_w2,
      dfeat_h, biasd, bias0, bias1, bias2, wpk, wldsg,
      wpk0, wpk1, wpk2, fcT0, fcT1, fcT2, w0b, w1b, w2b, wdb);

  // input projections (bf16 MFMA)
  mfma_gemm<false><<<8 * 512, 256, 0, stream>>>(mod0, w0b, bias0, umask, gx0, 300, 320, 512);
  mfma_gemm<false><<<4 * 512, 256, 0, stream>>>(mod1, w1b, bias1, umask, gx1, 100, 128, 256);
  mfma_gemm<false><<<8 * 512, 256, 0, stream>>>(mod2, w2b, bias2, umask, gx2, 512, 512, 512);

  // fused modality scans (mod0 | mod2 | mod1)
  ModScanArgs a;
  a.gx0 = gx0; a.gx1 = gx1; a.gx2 = gx2;
  a.wk0 = wpk0; a.wk1 = wpk1; a.wk2 = wpk2;
  a.ft0 = fcT0; a.ft1 = fcT1; a.ft2 = fcT2;
  a.fb0 = fc_b0; a.fb1 = fc_b1; a.fb2 = fc_b2;
  mod_scan<<<768, 256, 0, stream>>>(a, umask, dfeat_h);

  // dialogue input projection (bf16 MFMA, X already bf16)
  mfma_gemm<true><<<16 * 512, 256, 0, stream>>>(dfeat_h, wdb, biasd, nullptr, gxd, 256, 256, 1024);

  hipFuncSetAttribute(reinterpret_cast<const void*>(dlg_recur),
                      hipFuncAttributeMaxDynamicSharedMemorySize, DLG_LDS_BYTES);
  dlg_recur<<<256, 512, DLG_LDS_BYTES, stream>>>(gxd, wpk, wldsg, hall);

  out_head<<<M_ / 16, 256, 0, stream>>>(hall, fco_w, fco_b, sm_w, sm_b, (float*)d_out);
}

// Round 8
// 729.441 us; speedup vs baseline: 11.9974x; 1.2247x over previous
//
#include <hip/hip_runtime.h>

#define B_ 256
#define T_ 128
#define M_ (B_ * T_)
#define DH_ 256

__device__ __forceinline__ float sigf(float x) { return 1.0f / (1.0f + __expf(-x)); }
__device__ __forceinline__ float dot4(float4 a, float4 b) {
  return a.x * b.x + a.y * b.y + a.z * b.z + a.w * b.w;
}

typedef _Float16 half2v __attribute__((ext_vector_type(2)));
typedef short short8 __attribute__((ext_vector_type(8)));
typedef float f32x4 __attribute__((ext_vector_type(4)));

__device__ __forceinline__ float fdot2f(unsigned int w, unsigned int h, float acc) {
  half2v wv = __builtin_bit_cast(half2v, w);
  half2v hv = __builtin_bit_cast(half2v, h);
#if __has_builtin(__builtin_amdgcn_fdot2)
  return __builtin_amdgcn_fdot2(wv, hv, acc, false);
#else
  return acc + (float)wv[0] * (float)hv[0] + (float)wv[1] * (float)hv[1];
#endif
}
__device__ __forceinline__ unsigned int pk16(float a, float b) {
  unsigned short lo = __builtin_bit_cast(unsigned short, (_Float16)a);
  unsigned short hi = __builtin_bit_cast(unsigned short, (_Float16)b);
  return (unsigned int)lo | ((unsigned int)hi << 16);
}
__device__ __forceinline__ unsigned short bf16c(float x) {  // RNE f32->bf16
  unsigned int u = __builtin_bit_cast(unsigned int, x);
  return (unsigned short)((u + 0x7FFFu + ((u >> 16) & 1u)) >> 16);
}
__device__ __forceinline__ unsigned int bfpk(float a, float b) {
  return (unsigned int)bf16c(a) | ((unsigned int)bf16c(b) << 16);
}

// ---------------------------------------------------------------------------
// prep: combined biases; bf16 zero-padded GEMM weights (input projections,
// dialogue projection, and NOW the per-modality FC weights); fp16-packed
// recurrent weights (dialogue reg/LDS split + modality register rows).
// ---------------------------------------------------------------------------
__global__ void prep_kernel(const float* __restrict__ w_ih_d, const float* __restrict__ w_hh_d,
                            const float* __restrict__ b_ih_d, const float* __restrict__ b_hh_d,
                            const float* __restrict__ b_ih0, const float* __restrict__ b_hh0,
                            const float* __restrict__ b_ih1, const float* __restrict__ b_hh1,
                            const float* __restrict__ b_ih2, const float* __restrict__ b_hh2,
                            const float* __restrict__ w_hh0, const float* __restrict__ w_hh1,
                            const float* __restrict__ w_hh2,
                            const float* __restrict__ w_ih0, const float* __restrict__ w_ih1,
                            const float* __restrict__ w_ih2,
                            const float* __restrict__ fc_w0, const float* __restrict__ fc_w1,
                            const float* __restrict__ fc_w2,
                            unsigned short* __restrict__ dfeat_h,
                            float* __restrict__ biasd, float* __restrict__ bias0,
                            float* __restrict__ bias1, float* __restrict__ bias2,
                            unsigned int* __restrict__ wpk, unsigned int* __restrict__ wldsg,
                            unsigned int* __restrict__ wpk0, unsigned int* __restrict__ wpk1,
                            unsigned int* __restrict__ wpk2,
                            unsigned short* __restrict__ w0b, unsigned short* __restrict__ w1b,
                            unsigned short* __restrict__ w2b, unsigned short* __restrict__ wdb,
                            unsigned short* __restrict__ fcw0b, unsigned short* __restrict__ fcw1b,
                            unsigned short* __restrict__ fcw2b) {
  int idx = blockIdx.x * blockDim.x + threadIdx.x;
  int stride = gridDim.x * blockDim.x;
  // bf16 GEMM weights (K zero-padded to multiple of 32)
  for (int i = idx; i < 512 * 320; i += stride) {
    int r = i / 320, k = i % 320;
    w0b[i] = (k < 300) ? bf16c(w_ih0[(size_t)r * 300 + k]) : (unsigned short)0;
  }
  for (int i = idx; i < 256 * 128; i += stride) {
    int r = i >> 7, k = i & 127;
    w1b[i] = (k < 100) ? bf16c(w_ih1[(size_t)r * 100 + k]) : (unsigned short)0;
  }
  for (int i = idx; i < 512 * 512; i += stride) w2b[i] = bf16c(w_ih2[i]);
  for (int i = idx; i < 1024 * 256; i += stride) {
    int r = i >> 8, k = i & 255;
    wdb[i] = (k < 250) ? bf16c(w_ih_d[(size_t)r * 250 + k]) : (unsigned short)0;
  }
  // FC weights bf16, rows zero-padded to 128/64
  for (int i = idx; i < 128 * 128; i += stride) {
    int f = i >> 7, k = i & 127;
    fcw0b[i] = (f < 100) ? bf16c(fc_w0[(size_t)f * 128 + k]) : (unsigned short)0;
    fcw2b[i] = (f < 100) ? bf16c(fc_w2[(size_t)f * 128 + k]) : (unsigned short)0;
  }
  for (int i = idx; i < 64 * 64; i += stride) {
    int f = i >> 6, k = i & 63;
    fcw1b[i] = (f < 50) ? bf16c(fc_w1[(size_t)f * 64 + k]) : (unsigned short)0;
  }
  for (int i = idx; i < M_ * 6; i += stride)   // zero dfeat_h pad cols 250..255
    dfeat_h[(size_t)(i / 6) * 256 + 250 + (i % 6)] = 0;
  // dialogue recurrent weights fp16: reg part (pairs 0..95)
  for (int i = idx; i < 1024 * 96; i += stride) {
    int r = i / 96, k0 = (i % 96) * 2;
    wpk[i] = pk16(w_hh_d[(size_t)r * 256 + k0], w_hh_d[(size_t)r * 256 + k0 + 1]);
  }
  // dialogue LDS part, b128 layout: i = (jj*1024 + r)*4 + q, pair p = 96+4*jj+q
  for (int i = idx; i < 32768; i += stride) {
    int jj = i >> 12, rem = i & 4095, r = rem >> 2, q = rem & 3;
    int p = 96 + 4 * jj + q;
    wldsg[i] = pk16(w_hh_d[(size_t)r * 256 + 2 * p], w_hh_d[(size_t)r * 256 + 2 * p + 1]);
  }
  // modality recurrent weights (row-major packed pairs)
  for (int i = idx; i < 512 * 64; i += stride) {
    int r = i >> 6, p = (i & 63) * 2;
    wpk0[i] = pk16(w_hh0[(size_t)r * 128 + p], w_hh0[(size_t)r * 128 + p + 1]);
    wpk2[i] = pk16(w_hh2[(size_t)r * 128 + p], w_hh2[(size_t)r * 128 + p + 1]);
  }
  for (int i = idx; i < 256 * 32; i += stride) {
    int r = i >> 5, p = (i & 31) * 2;
    wpk1[i] = pk16(w_hh1[(size_t)r * 64 + p], w_hh1[(size_t)r * 64 + p + 1]);
  }
  for (int i = idx; i < 1024; i += stride) biasd[i] = b_ih_d[i] + b_hh_d[i];
  for (int i = idx; i < 512; i += stride) bias0[i] = b_ih0[i] + b_hh0[i];
  for (int i = idx; i < 256; i += stride) bias1[i] = b_ih1[i] + b_hh1[i];
  for (int i = idx; i < 512; i += stride) bias2[i] = b_ih2[i] + b_hh2[i];
}

// ---------------------------------------------------------------------------
// mfma_gemm: C[m][n] = scale * sum_k X[m][k]*W[n][k] + bias[n], bf16 MFMA.
// (unchanged — verified)
// ---------------------------------------------------------------------------
template <bool XF16>
__global__ __launch_bounds__(256) void mfma_gemm(
    const void* __restrict__ Xv, const unsigned short* __restrict__ Wb,
    const float* __restrict__ bias, const float* __restrict__ umask,
    float* __restrict__ C, int K, int Kp, int N) {
  __shared__ __align__(16) unsigned short Xs[64][40];
  __shared__ __align__(16) unsigned short Ws[64][40];
  const int tid = threadIdx.x;
  const int d = blockIdx.x;
  const int nx = N >> 6;
  const int n0 = ((d % (nx << 3)) >> 3) << 6;
  const int m0 = (((d / (nx << 3)) << 3) + (d & 7)) << 6;
  const int srow = tid >> 2, kq = tid & 3;
  const int w = tid >> 6, lane = tid & 63;
  const int lr = lane & 15, lk = lane >> 4;
  const float* Xf = nullptr;
  const unsigned short* Xh = nullptr;
  if constexpr (XF16) {
    Xh = (const unsigned short*)Xv + (size_t)(m0 + srow) * Kp;
  } else {
    const int t = m0 >> 8, b0 = m0 & 255;
    Xf = (const float*)Xv + ((size_t)(b0 + srow) * T_ + t) * K;
  }
  const unsigned short* Wr = Wb + (size_t)(n0 + srow) * Kp;
  f32x4 acc[4];
#pragma unroll
  for (int j = 0; j < 4; j++) acc[j] = (f32x4){0.f, 0.f, 0.f, 0.f};

  for (int k0 = 0; k0 < Kp; k0 += 32) {
    uint4 xa;
    const int kk = k0 + kq * 8;
    if constexpr (XF16) {
      xa = *reinterpret_cast<const uint4*>(Xh + kk);
    } else {
      float4 va = (kk + 3 < K) ? *reinterpret_cast<const float4*>(Xf + kk)
                               : make_float4(0.f, 0.f, 0.f, 0.f);
      float4 vb = (kk + 7 < K) ? *reinterpret_cast<const float4*>(Xf + kk + 4)
                               : make_float4(0.f, 0.f, 0.f, 0.f);
      xa.x = bfpk(va.x, va.y); xa.y = bfpk(va.z, va.w);
      xa.z = bfpk(vb.x, vb.y); xa.w = bfpk(vb.z, vb.w);
    }
    uint4 wv = *reinterpret_cast<const uint4*>(Wr + kk);
    __syncthreads();
    *reinterpret_cast<uint4*>(&Xs[srow][kq * 8]) = xa;
    *reinterpret_cast<uint4*>(&Ws[srow][kq * 8]) = wv;
    __syncthreads();
    short8 af = *reinterpret_cast<const short8*>(&Xs[w * 16 + lr][lk * 8]);
#pragma unroll
    for (int j = 0; j < 4; j++) {
      short8 bf = *reinterpret_cast<const short8*>(&Ws[j * 16 + lr][lk * 8]);
      acc[j] = __builtin_amdgcn_mfma_f32_16x16x32_bf16(af, bf, acc[j], 0, 0, 0);
    }
  }
#pragma unroll
  for (int j = 0; j < 4; j++) {
    const int col = n0 + j * 16 + lr;
    const float bv = bias[col];
#pragma unroll
    for (int r = 0; r < 4; r++) {
      const int mrow = m0 + w * 16 + lk * 4 + r;
      float um = 1.0f;
      if constexpr (!XF16)
        um = umask[((m0 & 255) + w * 16 + lk * 4 + r) * T_ + (m0 >> 8)];
      C[(size_t)mrow * N + col] = acc[j][r] * um + bv;
    }
  }
}

// ---------------------------------------------------------------------------
// fc_gemm: per-modality FC head as bf16 MFMA GEMM, moved OUT of the scan.
// dfeat[m][col0+f] = bf16(tanh(sum_k h[m][k]*fcw[f][k] + bias[f]) * umask),
// m = t*B+b. X = hallm bf16 [M][Kp]; W zero-row-padded to Np (64-mult).
// ---------------------------------------------------------------------------
__global__ __launch_bounds__(256) void fc_gemm(
    const unsigned short* __restrict__ Xh, const unsigned short* __restrict__ Wb,
    const float* __restrict__ fcb, const float* __restrict__ umask,
    unsigned short* __restrict__ dfeat_h, int Kp, int nx, int F, int col0) {
  __shared__ __align__(16) unsigned short Xs[64][40];
  __shared__ __align__(16) unsigned short Ws[64][40];
  const int tid = threadIdx.x;
  const int n0 = (blockIdx.x % nx) * 64;
  const int m0 = (blockIdx.x / nx) * 64;
  const int srow = tid >> 2, kq = tid & 3;
  const int w = tid >> 6, lane = tid & 63;
  const int lr = lane & 15, lk = lane >> 4;
  const unsigned short* Xp = Xh + (size_t)(m0 + srow) * Kp;
  const unsigned short* Wr = Wb + (size_t)(n0 + srow) * Kp;
  f32x4 acc[4];
#pragma unroll
  for (int j = 0; j < 4; j++) acc[j] = (f32x4){0.f, 0.f, 0.f, 0.f};
  for (int k0 = 0; k0 < Kp; k0 += 32) {
    const int kk = k0 + kq * 8;
    uint4 xa = *reinterpret_cast<const uint4*>(Xp + kk);
    uint4 wv = *reinterpret_cast<const uint4*>(Wr + kk);
    __syncthreads();
    *reinterpret_cast<uint4*>(&Xs[srow][kq * 8]) = xa;
    *reinterpret_cast<uint4*>(&Ws[srow][kq * 8]) = wv;
    __syncthreads();
    short8 af = *reinterpret_cast<const short8*>(&Xs[w * 16 + lr][lk * 8]);
#pragma unroll
    for (int j = 0; j < 4; j++) {
      short8 bf = *reinterpret_cast<const short8*>(&Ws[j * 16 + lr][lk * 8]);
      acc[j] = __builtin_amdgcn_mfma_f32_16x16x32_bf16(af, bf, acc[j], 0, 0, 0);
    }
  }
#pragma unroll
  for (int j = 0; j < 4; j++) {
    const int coln = n0 + j * 16 + lr;
    const float bv = (coln < F) ? fcb[coln] : 0.f;
#pragma unroll
    for (int r = 0; r < 4; r++) {
      const int mrow = m0 + w * 16 + lk * 4 + r;
      if (coln < F) {
        const int t = mrow >> 8, b = mrow & 255;
        float um = umask[b * T_ + t];
        dfeat_h[(size_t)mrow * 256 + col0 + coln] = bf16c(tanhf(acc[j][r] + bv) * um);
      }
    }
  }
}

// ---------------------------------------------------------------------------
// mod_scan: fused modality LSTM scans, FC REMOVED (h_t stored bf16 to hallm).
// 768 blocks x 256 threads; LDS now only gbuf+hbuf (2.3 KB).
// amdgpu_waves_per_eu(2,3): occupancy target 3 waves/EU -> 170-VGPR budget,
// so the 128 weight VGPRs stay genuinely register-resident (round-7 lesson:
// the allocator chased 4 waves/EU at 112 VGPR and re-loaded weights per step).
// ---------------------------------------------------------------------------
struct ModScanArgs {
  const float* gx0; const float* gx1; const float* gx2;
  const unsigned int* wk0; const unsigned int* wk1; const unsigned int* wk2;
  unsigned short* hm0; unsigned short* hm1; unsigned short* hm2;
};

__device__ __forceinline__ void mod_body128s(
    const float* __restrict__ gx, const unsigned int* __restrict__ wk,
    int b, unsigned short* __restrict__ hallm, unsigned int* smem) {
  float* gbuf = (float*)smem;          // 512 f32
  unsigned int* hbuf = smem + 512;     // 64 u32
  const int tid = threadIdx.x;
  uint4 wrA[16], wrB[16];
  {
    const uint4* wpA = reinterpret_cast<const uint4*>(wk + (size_t)tid * 64);
    const uint4* wpB = reinterpret_cast<const uint4*>(wk + (size_t)(tid + 256) * 64);
#pragma unroll
    for (int j = 0; j < 16; j++) { wrA[j] = wpA[j]; wrB[j] = wpB[j]; }
  }
  if (tid < 64) hbuf[tid] = 0u;
  float creg = 0.f;
  __syncthreads();
  const uint4* h4 = reinterpret_cast<const uint4*>(hbuf);
  const float* gp = gx + (size_t)b * 512 + tid;
  float gcA = gp[0], gcB = gp[256];
  for (int t = 0; t < T_; t++) {
    float gnA = 0.f, gnB = 0.f;
    if (t + 1 < T_) {
      gnA = gp[(size_t)(t + 1) * B_ * 512];
      gnB = gp[(size_t)(t + 1) * B_ * 512 + 256];
    }
    float a0 = 0.f, a1 = 0.f, a2 = 0.f, a3 = 0.f;
    float d0 = 0.f, d1 = 0.f, d2 = 0.f, d3 = 0.f;
#pragma unroll
    for (int j = 0; j < 16; j++) {
      uint4 hv = h4[j];
      a0 = fdot2f(wrA[j].x, hv.x, a0);
      a1 = fdot2f(wrA[j].y, hv.y, a1);
      a2 = fdot2f(wrA[j].z, hv.z, a2);
      a3 = fdot2f(wrA[j].w, hv.w, a3);
      d0 = fdot2f(wrB[j].x, hv.x, d0);
      d1 = fdot2f(wrB[j].y, hv.y, d1);
      d2 = fdot2f(wrB[j].z, hv.z, d2);
      d3 = fdot2f(wrB[j].w, hv.w, d3);
    }
    gbuf[tid] = (a0 + a1) + (a2 + a3) + gcA;      // gx includes bias + umask'd x
    gbuf[tid + 256] = (d0 + d1) + (d2 + d3) + gcB;
    gcA = gnA; gcB = gnB;
    __syncthreads();                               // S1: gates ready
    if (tid < 128) {
      float i_ = sigf(gbuf[tid]);
      float f_ = sigf(gbuf[128 + tid]);
      float g_ = tanhf(gbuf[256 + tid]);
      float o_ = sigf(gbuf[384 + tid]);
      float cc = f_ * creg + i_ * g_;
      creg = cc;
      float h2 = tanhf(o_ * tanhf(cc));            // extra tanh on hidden state
      hallm[((size_t)t * B_ + b) * 128 + tid] = bf16c(h2);
      float hp = __shfl_xor(h2, 1);
      if ((tid & 1) == 0) hbuf[tid >> 1] = pk16(h2, hp);
    }
    __syncthreads();                               // S2: h_t staged
  }
}

__device__ __forceinline__ void mod_body64s(
    const float* __restrict__ gx, const unsigned int* __restrict__ wk,
    int b, unsigned short* __restrict__ hallm, unsigned int* smem) {
  float* gbuf = (float*)smem;          // 256 f32
  unsigned int* hbuf = smem + 512;     // 32 u32
  const int tid = threadIdx.x;
  uint4 wr[8];
  {
    const uint4* wp = reinterpret_cast<const uint4*>(wk + (size_t)tid * 32);
#pragma unroll
    for (int j = 0; j < 8; j++) wr[j] = wp[j];
  }
  if (tid < 32) hbuf[tid] = 0u;
  float creg = 0.f;
  __syncthreads();
  const uint4* h4 = reinterpret_cast<const uint4*>(hbuf);
  const float* gp = gx + (size_t)b * 256 + tid;
  float gc = gp[0];
  for (int t = 0; t < T_; t++) {
    float gn = (t + 1 < T_) ? gp[(size_t)(t + 1) * B_ * 256] : 0.f;
    float a0 = 0.f, a1 = 0.f, a2 = 0.f, a3 = 0.f;
#pragma unroll
    for (int j = 0; j < 8; j++) {
      uint4 hv = h4[j];
      a0 = fdot2f(wr[j].x, hv.x, a0);
      a1 = fdot2f(wr[j].y, hv.y, a1);
      a2 = fdot2f(wr[j].z, hv.z, a2);
      a3 = fdot2f(wr[j].w, hv.w, a3);
    }
    gbuf[tid] = (a0 + a1) + (a2 + a3) + gc;
    gc = gn;
    __syncthreads();                               // S1
    if (tid < 64) {
      float i_ = sigf(gbuf[tid]);
      float f_ = sigf(gbuf[64 + tid]);
      float g_ = tanhf(gbuf[128 + tid]);
      float o_ = sigf(gbuf[192 + tid]);
      float cc = f_ * creg + i_ * g_;
      creg = cc;
      float h2 = tanhf(o_ * tanhf(cc));
      hallm[((size_t)t * B_ + b) * 64 + tid] = bf16c(h2);
      float hp = __shfl_xor(h2, 1);
      if ((tid & 1) == 0) hbuf[tid >> 1] = pk16(h2, hp);
    }
    __syncthreads();                               // S2
  }
}

__global__ __launch_bounds__(256)
__attribute__((amdgpu_waves_per_eu(2, 3)))
void mod_scan(ModScanArgs a, unsigned short* __restrict__ hm_unused) {
  __shared__ __align__(16) unsigned int smem[576];   // gbuf(512) | hbuf(64)
  const int blk = blockIdx.x;
  if (blk < 512) {
    const int mi = blk >> 8, b = blk & 255;
    mod_body128s(mi ? a.gx2 : a.gx0, mi ? a.wk2 : a.wk0, b,
                 mi ? a.hm2 : a.hm0, smem);
  } else {
    mod_body64s(a.gx1, a.wk1, blk - 512, a.hm1, smem);
  }
}

// ---------------------------------------------------------------------------
// dlg_recur: unchanged from round 7 (b128 LDS weight slice).
// ---------------------------------------------------------------------------
#define DLG_LDS_BYTES (131072 + 4096 + 512)

__global__ __launch_bounds__(512, 2) void dlg_recur(
    const float* __restrict__ gxd, const unsigned int* __restrict__ wpk,
    const unsigned int* __restrict__ wldsg, float* __restrict__ hall) {
  extern __shared__ char smem[];
  unsigned int* wl = (unsigned int*)smem;                       // [8][1024][4]
  float* gbuf = (float*)(smem + 131072);                        // [1024]
  _Float16* hbuf_h = (_Float16*)(smem + 131072 + 4096);         // [256]
  const uint4* hbuf4 = (const uint4*)hbuf_h;                    // [32]
  const uint4* wl4 = (const uint4*)wl;
  const int tid = threadIdx.x;
  const int b = blockIdx.x;

  for (int i = tid; i < 32768; i += 512) wl[i] = wldsg[i];
  unsigned int wr0[96], wr1[96];
  {
    const uint4* p0 = reinterpret_cast<const uint4*>(wpk + (size_t)tid * 96);
    const uint4* p1 = reinterpret_cast<const uint4*>(wpk + (size_t)(tid + 512) * 96);
#pragma unroll
    for (int j = 0; j < 24; j++) {
      uint4 v0 = p0[j], v1 = p1[j];
      wr0[4 * j + 0] = v0.x; wr0[4 * j + 1] = v0.y; wr0[4 * j + 2] = v0.z; wr0[4 * j + 3] = v0.w;
      wr1[4 * j + 0] = v1.x; wr1[4 * j + 1] = v1.y; wr1[4 * j + 2] = v1.z; wr1[4 * j + 3] = v1.w;
    }
  }
  if (tid < 32) reinterpret_cast<uint4*>(const_cast<_Float16*>(hbuf_h))[tid] = uint4{0, 0, 0, 0};
  float creg = 0.f;
  __syncthreads();

  const float* gbase = gxd + (size_t)b * 1024 + tid;
  float gc0 = gbase[0], gc1 = gbase[512];
  for (int t = 0; t < T_; t++) {
    float gn0 = 0.f, gn1 = 0.f;
    if (t + 1 < T_) {
      gn0 = gbase[(size_t)(t + 1) * B_ * 1024];
      gn1 = gbase[(size_t)(t + 1) * B_ * 1024 + 512];
    }
    float a0 = 0.f, a1 = 0.f;
#pragma unroll
    for (int j = 0; j < 24; j++) {          // pairs 0..95 (registers)
      uint4 hv = hbuf4[j];
      a0 = fdot2f(wr0[4 * j + 0], hv.x, a0); a1 = fdot2f(wr1[4 * j + 0], hv.x, a1);
      a0 = fdot2f(wr0[4 * j + 1], hv.y, a0); a1 = fdot2f(wr1[4 * j + 1], hv.y, a1);
      a0 = fdot2f(wr0[4 * j + 2], hv.z, a0); a1 = fdot2f(wr1[4 * j + 2], hv.z, a1);
      a0 = fdot2f(wr0[4 * j + 3], hv.w, a0); a1 = fdot2f(wr1[4 * j + 3], hv.w, a1);
    }
#pragma unroll
    for (int jj = 0; jj < 8; jj++) {        // pairs 96..127 (LDS, b128)
      uint4 hv = hbuf4[24 + jj];
      uint4 wa = wl4[jj * 1024 + tid];
      uint4 wc = wl4[jj * 1024 + tid + 512];
      a0 = fdot2f(wa.x, hv.x, a0); a1 = fdot2f(wc.x, hv.x, a1);
      a0 = fdot2f(wa.y, hv.y, a0); a1 = fdot2f(wc.y, hv.y, a1);
      a0 = fdot2f(wa.z, hv.z, a0); a1 = fdot2f(wc.z, hv.z, a1);
      a0 = fdot2f(wa.w, hv.w, a0); a1 = fdot2f(wc.w, hv.w, a1);
    }
    gbuf[tid] = a0 + gc0;
    gbuf[tid + 512] = a1 + gc1;
    __syncthreads();
    if (tid < DH_) {
      float i_ = sigf(gbuf[tid]);
      float f_ = sigf(gbuf[DH_ + tid]);
      float g_ = tanhf(gbuf[2 * DH_ + tid]);
      float o_ = sigf(gbuf[3 * DH_ + tid]);
      float c2 = f_ * creg + i_ * g_;
      creg = c2;
      float h2 = o_ * tanhf(c2);
      hall[((size_t)t * B_ + b) * DH_ + tid] = h2;
      hbuf_h[tid] = (_Float16)h2;
    }
    gc0 = gn0; gc1 = gn1;
    __syncthreads();
  }
}

// ---------------------------------------------------------------------------
// out_head: fc_out + tanh + smax + log_softmax (unchanged).
// ---------------------------------------------------------------------------
__global__ __launch_bounds__(256) void out_head(
    const float* __restrict__ hall, const float* __restrict__ fcow,
    const float* __restrict__ fcob, const float* __restrict__ smw,
    const float* __restrict__ smb, float* __restrict__ out) {
  __shared__ __align__(16) float h_lds[16][260];
  __shared__ __align__(16) float fco[16][132];
  __shared__ float lg[16][6];
  const int tid = threadIdx.x;
  const int m0 = blockIdx.x * 16;
  {
    const float* src = hall + (size_t)m0 * DH_;
    for (int e = tid; e < 1024; e += 256) {
      float4 v = reinterpret_cast<const float4*>(src)[e];
      const int r = e >> 6, k = (e & 63) * 4;
      *reinterpret_cast<float4*>(&h_lds[r][k]) = v;
    }
  }
  __syncthreads();
  {
    const int f = tid & 127, half = tid >> 7;
    float acc[8];
    const float fb = fcob[f];
#pragma unroll
    for (int r = 0; r < 8; r++) acc[r] = fb;
    const float* wrow = fcow + (size_t)f * DH_;
    for (int k = 0; k < DH_; k += 4) {
      float4 w4 = *reinterpret_cast<const float4*>(wrow + k);
#pragma unroll
      for (int r = 0; r < 8; r++)
        acc[r] += dot4(w4, *reinterpret_cast<const float4*>(&h_lds[half * 8 + r][k]));
    }
#pragma unroll
    for (int r = 0; r < 8; r++) fco[half * 8 + r][f] = tanhf(acc[r]);
  }
  __syncthreads();
  if (tid < 96) {
    const int r = tid / 6, cc = tid % 6;
    float a = smb[cc];
    const float* sw = smw + cc * 128;
#pragma unroll 4
    for (int k = 0; k < 128; k++) a += sw[k] * fco[r][k];
    lg[r][cc] = a;
  }
  __syncthreads();
  if (tid < 16) {
    const int m = m0 + tid;
    const int t = m >> 8, b = m & 255;
    float mx = lg[tid][0];
#pragma unroll
    for (int cc = 1; cc < 6; cc++) mx = fmaxf(mx, lg[tid][cc]);
    float ssum = 0.f;
#pragma unroll
    for (int cc = 0; cc < 6; cc++) ssum += __expf(lg[tid][cc] - mx);
    float lse = mx + logf(ssum);
#pragma unroll
    for (int cc = 0; cc < 6; cc++)
      out[((size_t)b * T_ + t) * 6 + cc] = lg[tid][cc] - lse;
  }
}

// ---------------------------------------------------------------------------
extern "C" void kernel_launch(void* const* d_in, const int* in_sizes, int n_in,
                              void* d_out, int out_size, void* d_ws, size_t ws_size,
                              hipStream_t stream) {
  const float* mod0  = (const float*)d_in[0];
  const float* mod1  = (const float*)d_in[1];
  const float* mod2  = (const float*)d_in[2];
  const float* umask = (const float*)d_in[3];
  const float* w_ih0 = (const float*)d_in[4];
  const float* w_hh0 = (const float*)d_in[5];
  const float* b_ih0 = (const float*)d_in[6];
  const float* b_hh0 = (const float*)d_in[7];
  const float* fc_w0 = (const float*)d_in[8];
  const float* fc_b0 = (const float*)d_in[9];
  const float* w_ih1 = (const float*)d_in[10];
  const float* w_hh1 = (const float*)d_in[11];
  const float* b_ih1 = (const float*)d_in[12];
  const float* b_hh1 = (const float*)d_in[13];
  const float* fc_w1 = (const float*)d_in[14];
  const float* fc_b1 = (const float*)d_in[15];
  const float* w_ih2 = (const float*)d_in[16];
  const float* w_hh2 = (const float*)d_in[17];
  const float* b_ih2 = (const float*)d_in[18];
  const float* b_hh2 = (const float*)d_in[19];
  const float* fc_w2 = (const float*)d_in[20];
  const float* fc_b2 = (const float*)d_in[21];
  const float* w_ih_d = (const float*)d_in[22];
  const float* w_hh_d = (const float*)d_in[23];
  const float* b_ih_d = (const float*)d_in[24];
  const float* b_hh_d = (const float*)d_in[25];
  const float* fco_w  = (const float*)d_in[26];
  const float* fco_b  = (const float*)d_in[27];
  const float* sm_w   = (const float*)d_in[28];
  const float* sm_b   = (const float*)d_in[29];

  // workspace layout (float units):
  //   [0, M*1280): gx0|gx1|gx2 -> reused as gxd [0,M*1024)
  //   [M*1024, M*1280): hallm0|hallm2|hallm1 (bf16, scan outputs)
  //                     -> later overwritten by hall (dialogue h, fp32)
  float* ws    = (float*)d_ws;
  float* gx0   = ws;                                  // M*512
  float* gx1   = gx0 + (size_t)M_ * 512;              // M*256
  float* gx2   = gx1 + (size_t)M_ * 256;              // M*512
  float* gxd   = ws;                                  // M*1024 (reuse)
  float* hall  = ws + (size_t)M_ * 1024;              // M*256 fp32
  unsigned short* hm0 = (unsigned short*)(ws + (size_t)M_ * 1024);  // M*128 bf16
  unsigned short* hm2 = hm0 + (size_t)M_ * 128;                     // M*128 bf16
  unsigned short* hm1 = hm2 + (size_t)M_ * 128;                     // M*64 bf16
  unsigned short* dfeat_h = (unsigned short*)(ws + (size_t)M_ * 1280);  // M*256 bf16
  float* tail  = ws + (size_t)M_ * 1408;
  float* biasd = tail;                                // 1024
  float* bias0 = biasd + 1024;                        // 512
  float* bias1 = bias0 + 512;                         // 256
  float* bias2 = bias1 + 256;                         // 512
  unsigned int* wpk   = (unsigned int*)(bias2 + 512); // 1024*96
  unsigned int* wldsg = wpk + 1024 * 96;              // 32768
  unsigned int* wpk0  = wldsg + 32768;                // 512*64
  unsigned int* wpk1  = wpk0 + 512 * 64;              // 256*32
  unsigned int* wpk2  = wpk1 + 256 * 32;              // 512*64
  unsigned short* w0b = (unsigned short*)(wpk2 + 512 * 64);  // 512*320
  unsigned short* w1b = w0b + 512 * 320;                     // 256*128
  unsigned short* w2b = w1b + 256 * 128;                     // 512*512
  unsigned short* wdb = w2b + 512 * 512;                     // 1024*256
  unsigned short* fcw0b = wdb + 1024 * 256;                  // 128*128
  unsigned short* fcw1b = fcw0b + 128 * 128;                 // 64*64
  unsigned short* fcw2b = fcw1b + 64 * 64;                   // 128*128

  prep_kernel<<<256, 256, 0, stream>>>(w_ih_d, w_hh_d, b_ih_d, b_hh_d,
      b_ih0, b_hh0, b_ih1, b_hh1, b_ih2, b_hh2,
      w_hh0, w_hh1, w_hh2, w_ih0, w_ih1, w_ih2, fc_w0, fc_w1, fc_w2,
      dfeat_h, biasd, bias0, bias1, bias2, wpk, wldsg,
      wpk0, wpk1, wpk2, w0b, w1b, w2b, wdb, fcw0b, fcw1b, fcw2b);

  // input projections (bf16 MFMA)
  mfma_gemm<false><<<8 * 512, 256, 0, stream>>>(mod0, w0b, bias0, umask, gx0, 300, 320, 512);
  mfma_gemm<false><<<4 * 512, 256, 0, stream>>>(mod1, w1b, bias1, umask, gx1, 100, 128, 256);
  mfma_gemm<false><<<8 * 512, 256, 0, stream>>>(mod2, w2b, bias2, umask, gx2, 512, 512, 512);

  // fused modality scans (FC evicted; h -> hallm bf16)
  ModScanArgs a;
  a.gx0 = gx0; a.gx1 = gx1; a.gx2 = gx2;
  a.wk0 = wpk0; a.wk1 = wpk1; a.wk2 = wpk2;
  a.hm0 = hm0; a.hm1 = hm1; a.hm2 = hm2;
  mod_scan<<<768, 256, 0, stream>>>(a, nullptr);

  // FC heads (bf16 MFMA) -> dfeat
  fc_gemm<<<512 * 2, 256, 0, stream>>>(hm0, fcw0b, fc_b0, umask, dfeat_h, 128, 2, 100, 0);
  fc_gemm<<<512 * 1, 256, 0, stream>>>(hm1, fcw1b, fc_b1, umask, dfeat_h, 64, 1, 50, 100);
  fc_gemm<<<512 * 2, 256, 0, stream>>>(hm2, fcw2b, fc_b2, umask, dfeat_h, 128, 2, 100, 150);

  // dialogue input projection (bf16 MFMA, X already bf16)
  mfma_gemm<true><<<16 * 512, 256, 0, stream>>>(dfeat_h, wdb, biasd, nullptr, gxd, 256, 256, 1024);

  hipFuncSetAttribute(reinterpret_cast<const void*>(dlg_recur),
                      hipFuncAttributeMaxDynamicSharedMemorySize, DLG_LDS_BYTES);
  dlg_recur<<<256, 512, DLG_LDS_BYTES, stream>>>(gxd, wpk, wldsg, hall);

  out_head<<<M_ / 16, 256, 0, stream>>>(hall, fco_w, fco_b, sm_w, sm_b, (float*)d_out);
}